// Round 1
// baseline (875.459 us; speedup 1.0000x reference)
//
#include <hip/hip_runtime.h>
#include <stdint.h>

#define NTOK 8192
#define DIM  1024
#define NE   8
#define NPAIR 28
#define OUTD 4096
#define MAXTILES 155   // >= sum_p ceil(cnt_p/64) worst case (128 + 27)

static __device__ __forceinline__ unsigned short f2bf(float f) {
    uint32_t u = __float_as_uint(f);
    u += 0x7fffu + ((u >> 16) & 1u);     // RNE
    return (unsigned short)(u >> 16);
}
static __device__ __forceinline__ float bf2f(unsigned short s) {
    return __uint_as_float(((uint32_t)s) << 16);
}

// ---------------- K0: W1[j][i][k][e] -> w1t[e][j][i][k] ----------------
__global__ __launch_bounds__(256) void k_w1t(const float* __restrict__ W1,
                                             float* __restrict__ w1t) {
    int t = blockIdx.x * 256 + threadIdx.x;          // 524288 total
    int k = t & 63, i = (t >> 6) & 31, j = (t >> 11) & 31, e = t >> 16;
    w1t[t] = W1[(((j * 32 + i) * 64 + k) * 8) + e];
}

// ---------------- K1: gate (fp32) + pair bucketing ----------------
__global__ __launch_bounds__(256) void k_gate(const float* __restrict__ x,
                                              const float* __restrict__ Wg,
                                              int* __restrict__ pairCnt,
                                              int* __restrict__ bucket,
                                              float* __restrict__ wgt) {
    __shared__ float sWg[NE][DIM];                   // 32 KB
    int tid = threadIdx.x;
    #pragma unroll
    for (int u = 0; u < 8; ++u) {
        int idx = u * 1024 + tid * 4;
        *(float4*)&sWg[0][idx] = *(const float4*)&Wg[idx];
    }
    __syncthreads();
    int w = tid >> 6, lane = tid & 63;
    int tok = blockIdx.x * 4 + w;
    float acc[NE];
    #pragma unroll
    for (int e = 0; e < NE; ++e) acc[e] = 0.f;
    const float* xr = x + (size_t)tok * DIM;
    #pragma unroll
    for (int c = 0; c < 4; ++c) {
        float4 xv = *(const float4*)&xr[c * 256 + lane * 4];
        #pragma unroll
        for (int e = 0; e < NE; ++e) {
            float4 wv = *(const float4*)&sWg[e][c * 256 + lane * 4];
            acc[e] += xv.x * wv.x + xv.y * wv.y + xv.z * wv.z + xv.w * wv.w;
        }
    }
    #pragma unroll
    for (int e = 0; e < NE; ++e)
        #pragma unroll
        for (int off = 32; off > 0; off >>= 1)
            acc[e] += __shfl_xor(acc[e], off, 64);
    if (lane == 0) {
        int i1 = 0; float v1 = acc[0];
        for (int e = 1; e < NE; ++e) if (acc[e] > v1) { v1 = acc[e]; i1 = e; }
        int i2 = -1; float v2 = -3.4e38f;
        for (int e = 0; e < NE; ++e) { if (e == i1) continue; if (acc[e] > v2) { v2 = acc[e]; i2 = e; } }
        float ex = expf(v2 - v1);                    // v2 <= v1
        float s  = 1.f / (1.f + ex);
        float w1v = s + 1e-6f;                       // weight of i1
        float w2v = ex * s + 1e-6f;                  // weight of i2
        int ea = min(i1, i2), eb = max(i1, i2);
        float wa = (i1 < i2) ? w1v : w2v;
        float wb = (i1 < i2) ? w2v : w1v;
        wgt[tok * 2 + 0] = wa;
        wgt[tok * 2 + 1] = wb;
        int pid = ea * 7 - (ea * (ea - 1)) / 2 + (eb - ea - 1);
        int pos = atomicAdd(&pairCnt[pid], 1);
        bucket[pid * NTOK + pos] = tok;
    }
}

// ---------------- K2b: slot -> token map (scan 28 counts) ----------------
__global__ __launch_bounds__(256) void k_slots(const int* __restrict__ pairCnt,
                                               const int* __restrict__ bucket,
                                               int* __restrict__ tokmap) {
    int s = blockIdx.x * 256 + threadIdx.x;          // 8192 threads
    int off = 0;
    for (int p = 0; p < NPAIR; ++p) {
        int c = pairCnt[p];
        if (s < off + c) { tokmap[s] = bucket[p * NTOK + (s - off)]; return; }
        off += c;
    }
}

// ---------------- K2c: gather + transpose x -> xgT[d][slot] ----------------
__global__ __launch_bounds__(256) void k_xgt(const float* __restrict__ x,
                                             const int* __restrict__ tokmap,
                                             float* __restrict__ xgT) {
    __shared__ float tile[64][65];
    int bs = blockIdx.x & 127, bd = blockIdx.x >> 7; // 128 s-tiles x 16 d-tiles
    int s0 = bs * 64, d0 = bd * 64;
    int tid = threadIdx.x;
    int sl = tid >> 2, q = tid & 3;
    int tok = tokmap[s0 + sl];
    const float* xr = x + (size_t)tok * DIM + d0 + q * 16;
    #pragma unroll
    for (int c = 0; c < 4; ++c) {
        float4 v = *(const float4*)&xr[c * 4];
        tile[sl][q * 16 + c * 4 + 0] = v.x;
        tile[sl][q * 16 + c * 4 + 1] = v.y;
        tile[sl][q * 16 + c * 4 + 2] = v.z;
        tile[sl][q * 16 + c * 4 + 3] = v.w;
    }
    __syncthreads();
    int dl = tid >> 2;
    float* orow = xgT + (size_t)(d0 + dl) * NTOK + s0 + q * 16;
    #pragma unroll
    for (int c = 0; c < 4; ++c) {
        float4 v;
        v.x = tile[q * 16 + c * 4 + 0][dl];
        v.y = tile[q * 16 + c * 4 + 1][dl];
        v.z = tile[q * 16 + c * 4 + 2][dl];
        v.w = tile[q * 16 + c * 4 + 3][dl];
        *(float4*)&orow[c * 4] = v;
    }
}

// ---------------- K3: fused BTT per pair-tile x k-split ----------------
__global__ __launch_bounds__(256, 2) void k_main(const float* __restrict__ W2,
                                                 const float* __restrict__ bias,
                                                 const float* __restrict__ w1t,
                                                 const float* __restrict__ xgT,
                                                 const int* __restrict__ tokmap,
                                                 const float* __restrict__ wgt,
                                                 const int* __restrict__ pairCnt,
                                                 float* __restrict__ out) {
    // zs[j][e][kkq][t][4] bf16 : 64 KB
    __shared__ unsigned short zs[32][2][2][64][4];

    int bid = blockIdx.x;
    int kb = bid & 7, tb = bid >> 3;

    int p = -1, s0 = 0, cnt = 0;
    {
        int toff = 0, soff = 0;
        for (int q = 0; q < NPAIR; ++q) {
            int c = pairCnt[q];
            int nt = (c + 63) >> 6;
            if (p < 0 && tb < toff + nt) {
                int lt = tb - toff;
                p = q;
                s0 = soff + lt * 64;
                cnt = min(64, c - lt * 64);
            }
            toff += nt; soff += c;
        }
    }
    if (p < 0) return;
    p  = __builtin_amdgcn_readfirstlane(p);
    s0 = __builtin_amdgcn_readfirstlane(s0);

    int a = 0, r = p;
    while (r >= 7 - a) { r -= 7 - a; ++a; }
    int ea = a, eb = a + 1 + r;

    int tid = threadIdx.x, w = tid >> 6, lane = tid & 63;
    int sm = min(s0 + lane, NTOK - 1);
    bool valid = lane < cnt;
    int tok = tokmap[sm];
    float2 wv2 = *(const float2*)&wgt[tok * 2];
    float wsc[2] = { wv2.x, wv2.y };

    // ---- phase 1: z[j][e][kb*8+kk] for this wave's 8 j's ----
    for (int jj = 0; jj < 8; ++jj) {
        int j = w * 8 + jj;
        float acc[2][8];
        #pragma unroll
        for (int e = 0; e < 2; ++e)
            #pragma unroll
            for (int c = 0; c < 8; ++c) acc[e][c] = 0.f;

        const float* xcol = xgT + (size_t)j * NTOK + sm;
        const float* w1a = w1t + (((size_t)ea * 32 + j) * 32) * 64 + kb * 8;
        const float* w1b = w1t + (((size_t)eb * 32 + j) * 32) * 64 + kb * 8;

        #pragma unroll 4
        for (int i = 0; i < 32; ++i) {
            float xv = xcol[(size_t)i * 32 * NTOK];
            const float* pa = w1a + i * 64;
            const float* pb = w1b + i * 64;
            #pragma unroll
            for (int c = 0; c < 8; ++c) acc[0][c] = fmaf(xv, pa[c], acc[0][c]);
            #pragma unroll
            for (int c = 0; c < 8; ++c) acc[1][c] = fmaf(xv, pb[c], acc[1][c]);
        }
        #pragma unroll
        for (int e = 0; e < 2; ++e) {
            float g = wsc[e];
            #pragma unroll
            for (int kq = 0; kq < 2; ++kq) {
                ushort4 pk;
                pk.x = f2bf(acc[e][kq * 4 + 0] * g);
                pk.y = f2bf(acc[e][kq * 4 + 1] * g);
                pk.z = f2bf(acc[e][kq * 4 + 2] * g);
                pk.w = f2bf(acc[e][kq * 4 + 3] * g);
                *(ushort4*)&zs[j][e][kq][lane][0] = pk;
            }
        }
    }
    __syncthreads();

    // ---- phase 2: y[t][kb*8+kk][w*16+lt] ----
    float y[8][16];
    #pragma unroll
    for (int kk = 0; kk < 8; ++kk)
        #pragma unroll
        for (int lt = 0; lt < 16; ++lt) y[kk][lt] = 0.f;

    for (int je = 0; je < 64; ++je) {
        int j = je >> 1, e = je & 1;
        ushort4 z0 = *(const ushort4*)&zs[j][e][0][lane][0];
        ushort4 z1 = *(const ushort4*)&zs[j][e][1][lane][0];
        float zf[8];
        zf[0] = bf2f(z0.x); zf[1] = bf2f(z0.y); zf[2] = bf2f(z0.z); zf[3] = bf2f(z0.w);
        zf[4] = bf2f(z1.x); zf[5] = bf2f(z1.y); zf[6] = bf2f(z1.z); zf[7] = bf2f(z1.w);
        int eid = e ? eb : ea;
        const float* w2p = W2 + (((size_t)eid * 64 + kb * 8) * 32 + j) * 64 + w * 16;
        #pragma unroll
        for (int kk = 0; kk < 8; ++kk) {
            const float* wr = w2p + (size_t)kk * 2048;   // next k: stride 32*64
            float z = zf[kk];
            #pragma unroll
            for (int lt = 0; lt < 16; ++lt)
                y[kk][lt] = fmaf(z, wr[lt], y[kk][lt]);
        }
    }

    if (valid) {
        float* orow = out + (size_t)tok * OUTD + (kb * 8) * 64 + w * 16;
        #pragma unroll
        for (int kk = 0; kk < 8; ++kk) {
            const float* br = bias + (kb * 8 + kk) * 64 + w * 16;
            #pragma unroll
            for (int c = 0; c < 4; ++c) {
                float4 bv = *(const float4*)&br[c * 4];
                float4 ov;
                ov.x = y[kk][c * 4 + 0] + bv.x;
                ov.y = y[kk][c * 4 + 1] + bv.y;
                ov.z = y[kk][c * 4 + 2] + bv.z;
                ov.w = y[kk][c * 4 + 3] + bv.w;
                *(float4*)&orow[(size_t)kk * 64 + c * 4] = ov;
            }
        }
    }
}

extern "C" void kernel_launch(void* const* d_in, const int* in_sizes, int n_in,
                              void* d_out, int out_size, void* d_ws, size_t ws_size,
                              hipStream_t stream) {
    const float* x  = (const float*)d_in[0];
    const float* Wg = (const float*)d_in[1];
    const float* W1 = (const float*)d_in[2];
    const float* W2 = (const float*)d_in[3];
    const float* b  = (const float*)d_in[4];
    float* out = (float*)d_out;

    float* w1t   = (float*)d_ws;                       // 524288 f
    float* xgT   = w1t + 524288;                       // 8192*1024 f
    int*   tokmap = (int*)(xgT + (size_t)NTOK * DIM);  // 8192 i
    float* wgt   = (float*)(tokmap + NTOK);            // 16384 f
    int*   pairCnt = (int*)(wgt + 2 * NTOK);           // 32 i
    int*   bucket  = pairCnt + 32;                     // 28*8192 i

    hipMemsetAsync(pairCnt, 0, 32 * sizeof(int), stream);
    k_w1t  <<<2048, 256, 0, stream>>>(W1, w1t);
    k_gate <<<2048, 256, 0, stream>>>(x, Wg, pairCnt, bucket, wgt);
    k_slots<<<32,   256, 0, stream>>>(pairCnt, bucket, tokmap);
    k_xgt  <<<2048, 256, 0, stream>>>(x, tokmap, xgT);
    k_main <<<MAXTILES * 8, 256, 0, stream>>>(W2, b, w1t, xgT, tokmap, wgt, pairCnt, out);
}

// Round 2
// 770.950 us; speedup vs baseline: 1.1356x; 1.1356x over previous
//
#include <hip/hip_runtime.h>
#include <stdint.h>

#define NTOK 8192
#define DIM  1024
#define NE   8
#define NPAIR 28
#define OUTD 4096
#define MAXTILES 155   // >= sum_p ceil(cnt_p/64) worst case (128 + 27)

static __device__ __forceinline__ unsigned short f2bf(float f) {
    uint32_t u = __float_as_uint(f);
    u += 0x7fffu + ((u >> 16) & 1u);     // RNE
    return (unsigned short)(u >> 16);
}
static __device__ __forceinline__ float bf2f(unsigned short s) {
    return __uint_as_float(((uint32_t)s) << 16);
}

// ---------------- K0: W1[j][i][k][e] -> w1t[e][j][i][k] ----------------
__global__ __launch_bounds__(256) void k_w1t(const float* __restrict__ W1,
                                             float* __restrict__ w1t) {
    int t = blockIdx.x * 256 + threadIdx.x;          // 524288 total
    int k = t & 63, i = (t >> 6) & 31, j = (t >> 11) & 31, e = t >> 16;
    w1t[t] = W1[(((j * 32 + i) * 64 + k) * 8) + e];
}

// ---------------- K1: gate (fp32) + pair bucketing ----------------
__global__ __launch_bounds__(256) void k_gate(const float* __restrict__ x,
                                              const float* __restrict__ Wg,
                                              int* __restrict__ pairCnt,
                                              int* __restrict__ bucket,
                                              float* __restrict__ wgt) {
    __shared__ float sWg[NE][DIM];                   // 32 KB
    int tid = threadIdx.x;
    #pragma unroll
    for (int u = 0; u < 8; ++u) {
        int idx = u * 1024 + tid * 4;
        *(float4*)&sWg[0][idx] = *(const float4*)&Wg[idx];
    }
    __syncthreads();
    int w = tid >> 6, lane = tid & 63;
    int tok = blockIdx.x * 4 + w;
    float acc[NE];
    #pragma unroll
    for (int e = 0; e < NE; ++e) acc[e] = 0.f;
    const float* xr = x + (size_t)tok * DIM;
    #pragma unroll
    for (int c = 0; c < 4; ++c) {
        float4 xv = *(const float4*)&xr[c * 256 + lane * 4];
        #pragma unroll
        for (int e = 0; e < NE; ++e) {
            float4 wv = *(const float4*)&sWg[e][c * 256 + lane * 4];
            acc[e] += xv.x * wv.x + xv.y * wv.y + xv.z * wv.z + xv.w * wv.w;
        }
    }
    #pragma unroll
    for (int e = 0; e < NE; ++e)
        #pragma unroll
        for (int off = 32; off > 0; off >>= 1)
            acc[e] += __shfl_xor(acc[e], off, 64);
    if (lane == 0) {
        int i1 = 0; float v1 = acc[0];
        for (int e = 1; e < NE; ++e) if (acc[e] > v1) { v1 = acc[e]; i1 = e; }
        int i2 = -1; float v2 = -3.4e38f;
        for (int e = 0; e < NE; ++e) { if (e == i1) continue; if (acc[e] > v2) { v2 = acc[e]; i2 = e; } }
        float ex = expf(v2 - v1);                    // v2 <= v1
        float s  = 1.f / (1.f + ex);
        float w1v = s + 1e-6f;                       // weight of i1
        float w2v = ex * s + 1e-6f;                  // weight of i2
        int ea = min(i1, i2), eb = max(i1, i2);
        float wa = (i1 < i2) ? w1v : w2v;
        float wb = (i1 < i2) ? w2v : w1v;
        wgt[tok * 2 + 0] = wa;
        wgt[tok * 2 + 1] = wb;
        int pid = ea * 7 - (ea * (ea - 1)) / 2 + (eb - ea - 1);
        int pos = atomicAdd(&pairCnt[pid], 1);
        bucket[pid * NTOK + pos] = tok;
    }
}

// ---------------- K2b: slot -> token map (scan 28 counts) ----------------
__global__ __launch_bounds__(256) void k_slots(const int* __restrict__ pairCnt,
                                               const int* __restrict__ bucket,
                                               int* __restrict__ tokmap) {
    int s = blockIdx.x * 256 + threadIdx.x;          // 8192 threads
    int off = 0;
    for (int p = 0; p < NPAIR; ++p) {
        int c = pairCnt[p];
        if (s < off + c) { tokmap[s] = bucket[p * NTOK + (s - off)]; return; }
        off += c;
    }
}

// ---- K2c: gather + transpose x -> xg2[(j*32+i)][slot], d = i*32+j ----
__global__ __launch_bounds__(256) void k_xgt(const float* __restrict__ x,
                                             const int* __restrict__ tokmap,
                                             float* __restrict__ xg2) {
    __shared__ float tile[64][65];
    int bs = blockIdx.x & 127, bd = blockIdx.x >> 7; // 128 s-tiles x 16 d-tiles
    int s0 = bs * 64, d0 = bd * 64;
    int tid = threadIdx.x;
    int sl = tid >> 2, q = tid & 3;
    int tok = tokmap[s0 + sl];
    const float* xr = x + (size_t)tok * DIM + d0 + q * 16;
    #pragma unroll
    for (int c = 0; c < 4; ++c) {
        float4 v = *(const float4*)&xr[c * 4];
        tile[sl][q * 16 + c * 4 + 0] = v.x;
        tile[sl][q * 16 + c * 4 + 1] = v.y;
        tile[sl][q * 16 + c * 4 + 2] = v.z;
        tile[sl][q * 16 + c * 4 + 3] = v.w;
    }
    __syncthreads();
    int dl = tid >> 2;
    int d = d0 + dl;
    int row = (d & 31) * 32 + (d >> 5);              // row = j*32 + i
    float* orow = xg2 + (size_t)row * NTOK + s0 + q * 16;
    #pragma unroll
    for (int c = 0; c < 4; ++c) {
        float4 v;
        v.x = tile[q * 16 + c * 4 + 0][dl];
        v.y = tile[q * 16 + c * 4 + 1][dl];
        v.z = tile[q * 16 + c * 4 + 2][dl];
        v.w = tile[q * 16 + c * 4 + 3][dl];
        *(float4*)&orow[c * 4] = v;
    }
}

// ---------------- K3: fused BTT, 512 thr, j-chunk double-buffered ----------------
__global__ __launch_bounds__(512, 4) void k_main(const float* __restrict__ W2,
                                                 const float* __restrict__ bias,
                                                 const float* __restrict__ w1t,
                                                 const float* __restrict__ xg2,
                                                 const int* __restrict__ tokmap,
                                                 const float* __restrict__ wgt,
                                                 const int* __restrict__ pairCnt,
                                                 float* __restrict__ out) {
    // zs[buf][jloc][e][kq][t][4] bf16 : 2 x 16 KB = 32 KB
    __shared__ unsigned short zs[2][8][2][2][64][4];

    int bid = blockIdx.x;
    int kb = bid & 7, tb = bid >> 3;   // kb == XCD id (round-robin) -> W1/W2 kb-slices L2-resident

    int p = -1, s0 = 0, cnt = 0;
    {
        int toff = 0, soff = 0;
        for (int q = 0; q < NPAIR; ++q) {
            int c = pairCnt[q];
            int nt = (c + 63) >> 6;
            if (p < 0 && tb < toff + nt) {
                int lt = tb - toff;
                p = q;
                s0 = soff + lt * 64;
                cnt = min(64, c - lt * 64);
            }
            toff += nt; soff += c;
        }
    }
    if (p < 0) return;
    p  = __builtin_amdgcn_readfirstlane(p);
    s0 = __builtin_amdgcn_readfirstlane(s0);

    int a = 0, r = p;
    while (r >= 7 - a) { r -= 7 - a; ++a; }
    int ea = a, eb = a + 1 + r;

    int tid = threadIdx.x, w = tid >> 6, lane = tid & 63;
    int sm = min(s0 + lane, NTOK - 1);
    bool valid = lane < cnt;
    int tok = tokmap[sm];
    float2 wv2 = *(const float2*)&wgt[tok * 2];
    float wsc[2] = { wv2.x, wv2.y };

    float y[8][8];
    #pragma unroll
    for (int kk = 0; kk < 8; ++kk)
        #pragma unroll
        for (int lt = 0; lt < 8; ++lt) y[kk][lt] = 0.f;

    // phase 1 for chunk c into buffer b: wave w computes global j = c*8 + w
    auto phase1 = [&](int c, int b) {
        int jg = c * 8 + w;
        float acc[2][8];
        #pragma unroll
        for (int e = 0; e < 2; ++e)
            #pragma unroll
            for (int q = 0; q < 8; ++q) acc[e][q] = 0.f;
        const float* xcol = xg2 + (size_t)(jg * 32) * NTOK + sm;
        const float* w1a = w1t + (((size_t)ea * 32 + jg) * 32) * 64 + kb * 8;
        const float* w1b = w1t + (((size_t)eb * 32 + jg) * 32) * 64 + kb * 8;
        #pragma unroll 4
        for (int i = 0; i < 32; ++i) {
            float xv = xcol[(size_t)i * NTOK];
            float4 a0 = *(const float4*)(w1a + i * 64);
            float4 a1 = *(const float4*)(w1a + i * 64 + 4);
            float4 b0 = *(const float4*)(w1b + i * 64);
            float4 b1 = *(const float4*)(w1b + i * 64 + 4);
            acc[0][0] = fmaf(xv, a0.x, acc[0][0]);
            acc[0][1] = fmaf(xv, a0.y, acc[0][1]);
            acc[0][2] = fmaf(xv, a0.z, acc[0][2]);
            acc[0][3] = fmaf(xv, a0.w, acc[0][3]);
            acc[0][4] = fmaf(xv, a1.x, acc[0][4]);
            acc[0][5] = fmaf(xv, a1.y, acc[0][5]);
            acc[0][6] = fmaf(xv, a1.z, acc[0][6]);
            acc[0][7] = fmaf(xv, a1.w, acc[0][7]);
            acc[1][0] = fmaf(xv, b0.x, acc[1][0]);
            acc[1][1] = fmaf(xv, b0.y, acc[1][1]);
            acc[1][2] = fmaf(xv, b0.z, acc[1][2]);
            acc[1][3] = fmaf(xv, b0.w, acc[1][3]);
            acc[1][4] = fmaf(xv, b1.x, acc[1][4]);
            acc[1][5] = fmaf(xv, b1.y, acc[1][5]);
            acc[1][6] = fmaf(xv, b1.z, acc[1][6]);
            acc[1][7] = fmaf(xv, b1.w, acc[1][7]);
        }
        #pragma unroll
        for (int e = 0; e < 2; ++e) {
            float g = wsc[e];
            #pragma unroll
            for (int kq = 0; kq < 2; ++kq) {
                ushort4 pk;
                pk.x = f2bf(acc[e][kq * 4 + 0] * g);
                pk.y = f2bf(acc[e][kq * 4 + 1] * g);
                pk.z = f2bf(acc[e][kq * 4 + 2] * g);
                pk.w = f2bf(acc[e][kq * 4 + 3] * g);
                *(ushort4*)&zs[b][w][e][kq][lane][0] = pk;
            }
        }
    };

    // phase 2 for chunk c from buffer b: wave w handles l-range w*8..w*8+8
    auto phase2 = [&](int c, int b) {
        #pragma unroll
        for (int je = 0; je < 16; ++je) {
            int j = je >> 1, e = je & 1;
            ushort4 z0 = *(const ushort4*)&zs[b][j][e][0][lane][0];
            ushort4 z1 = *(const ushort4*)&zs[b][j][e][1][lane][0];
            float zf[8];
            zf[0] = bf2f(z0.x); zf[1] = bf2f(z0.y); zf[2] = bf2f(z0.z); zf[3] = bf2f(z0.w);
            zf[4] = bf2f(z1.x); zf[5] = bf2f(z1.y); zf[6] = bf2f(z1.z); zf[7] = bf2f(z1.w);
            int eid = e ? eb : ea;
            const float* w2p = W2 + (((size_t)eid * 64 + kb * 8) * 32 + (c * 8 + j)) * 64 + w * 8;
            #pragma unroll
            for (int kk = 0; kk < 8; ++kk) {
                const float* wr = w2p + (size_t)kk * 2048;   // next k: stride 32*64
                float4 u0 = *(const float4*)wr;
                float4 u1 = *(const float4*)(wr + 4);
                float z = zf[kk];
                y[kk][0] = fmaf(z, u0.x, y[kk][0]);
                y[kk][1] = fmaf(z, u0.y, y[kk][1]);
                y[kk][2] = fmaf(z, u0.z, y[kk][2]);
                y[kk][3] = fmaf(z, u0.w, y[kk][3]);
                y[kk][4] = fmaf(z, u1.x, y[kk][4]);
                y[kk][5] = fmaf(z, u1.y, y[kk][5]);
                y[kk][6] = fmaf(z, u1.z, y[kk][6]);
                y[kk][7] = fmaf(z, u1.w, y[kk][7]);
            }
        }
    };

    phase1(0, 0);
    __syncthreads();
    #pragma unroll
    for (int c = 0; c < 4; ++c) {
        if (c < 3) phase1(c + 1, (c + 1) & 1);
        phase2(c, c & 1);
        __syncthreads();
    }

    if (valid) {
        float* orow = out + (size_t)tok * OUTD + (kb * 8) * 64 + w * 8;
        #pragma unroll
        for (int kk = 0; kk < 8; ++kk) {
            const float* br = bias + (kb * 8 + kk) * 64 + w * 8;
            float4 b0 = *(const float4*)br;
            float4 b1 = *(const float4*)(br + 4);
            float4 o0, o1;
            o0.x = y[kk][0] + b0.x;
            o0.y = y[kk][1] + b0.y;
            o0.z = y[kk][2] + b0.z;
            o0.w = y[kk][3] + b0.w;
            o1.x = y[kk][4] + b1.x;
            o1.y = y[kk][5] + b1.y;
            o1.z = y[kk][6] + b1.z;
            o1.w = y[kk][7] + b1.w;
            *(float4*)&orow[(size_t)kk * 64]     = o0;
            *(float4*)&orow[(size_t)kk * 64 + 4] = o1;
        }
    }
}

extern "C" void kernel_launch(void* const* d_in, const int* in_sizes, int n_in,
                              void* d_out, int out_size, void* d_ws, size_t ws_size,
                              hipStream_t stream) {
    const float* x  = (const float*)d_in[0];
    const float* Wg = (const float*)d_in[1];
    const float* W1 = (const float*)d_in[2];
    const float* W2 = (const float*)d_in[3];
    const float* b  = (const float*)d_in[4];
    float* out = (float*)d_out;

    float* w1t   = (float*)d_ws;                       // 524288 f
    float* xg2   = w1t + 524288;                       // 8192*1024 f
    int*   tokmap = (int*)(xg2 + (size_t)NTOK * DIM);  // 8192 i
    float* wgt   = (float*)(tokmap + NTOK);            // 16384 f
    int*   pairCnt = (int*)(wgt + 2 * NTOK);           // 32 i
    int*   bucket  = pairCnt + 32;                     // 28*8192 i

    hipMemsetAsync(pairCnt, 0, 32 * sizeof(int), stream);
    k_w1t  <<<2048, 256, 0, stream>>>(W1, w1t);
    k_gate <<<2048, 256, 0, stream>>>(x, Wg, pairCnt, bucket, wgt);
    k_slots<<<32,   256, 0, stream>>>(pairCnt, bucket, tokmap);
    k_xgt  <<<2048, 256, 0, stream>>>(x, tokmap, xg2);
    k_main <<<MAXTILES * 8, 512, 0, stream>>>(W2, b, w1t, xg2, tokmap, wgt, pairCnt, out);
}

// Round 3
// 703.171 us; speedup vs baseline: 1.2450x; 1.0964x over previous
//
#include <hip/hip_runtime.h>
#include <stdint.h>

#define NTOK 8192
#define DIM  1024
#define NE   8
#define NPAIR 28
#define OUTD 4096
#define MAXTILES 155   // >= sum_p ceil(cnt_p/64) worst case (128 + 27)

static __device__ __forceinline__ unsigned short f2bf(float f) {
    uint32_t u = __float_as_uint(f);
    u += 0x7fffu + ((u >> 16) & 1u);     // RNE
    return (unsigned short)(u >> 16);
}

// ---------------- K0: W1[j][i][k][e] -> w1t2[kb][e][j][i][kk] ----------------
__global__ __launch_bounds__(256) void k_w1t2(const float* __restrict__ W1,
                                              float* __restrict__ w1t2) {
    int t = blockIdx.x * 256 + threadIdx.x;          // 524288 total
    int kk = t & 7, i = (t >> 3) & 31, j = (t >> 8) & 31, e = (t >> 13) & 7, kb = (t >> 16) & 7;
    w1t2[t] = W1[(((j * 32 + i) * 64) + kb * 8 + kk) * 8 + e];
}

// ---------------- K1: gate (fp32) + pair bucketing ----------------
__global__ __launch_bounds__(256) void k_gate(const float* __restrict__ x,
                                              const float* __restrict__ Wg,
                                              int* __restrict__ pairCnt,
                                              int* __restrict__ bucket,
                                              float* __restrict__ wgt) {
    __shared__ float sWg[NE][DIM];                   // 32 KB
    int tid = threadIdx.x;
    #pragma unroll
    for (int u = 0; u < 8; ++u) {
        int idx = u * 1024 + tid * 4;
        *(float4*)&sWg[0][idx] = *(const float4*)&Wg[idx];
    }
    __syncthreads();
    int w = tid >> 6, lane = tid & 63;
    int tok = blockIdx.x * 4 + w;
    float acc[NE];
    #pragma unroll
    for (int e = 0; e < NE; ++e) acc[e] = 0.f;
    const float* xr = x + (size_t)tok * DIM;
    #pragma unroll
    for (int c = 0; c < 4; ++c) {
        float4 xv = *(const float4*)&xr[c * 256 + lane * 4];
        #pragma unroll
        for (int e = 0; e < NE; ++e) {
            float4 wv = *(const float4*)&sWg[e][c * 256 + lane * 4];
            acc[e] += xv.x * wv.x + xv.y * wv.y + xv.z * wv.z + xv.w * wv.w;
        }
    }
    #pragma unroll
    for (int e = 0; e < NE; ++e)
        #pragma unroll
        for (int off = 32; off > 0; off >>= 1)
            acc[e] += __shfl_xor(acc[e], off, 64);
    if (lane == 0) {
        int i1 = 0; float v1 = acc[0];
        for (int e = 1; e < NE; ++e) if (acc[e] > v1) { v1 = acc[e]; i1 = e; }
        int i2 = -1; float v2 = -3.4e38f;
        for (int e = 0; e < NE; ++e) { if (e == i1) continue; if (acc[e] > v2) { v2 = acc[e]; i2 = e; } }
        float ex = expf(v2 - v1);                    // v2 <= v1
        float s  = 1.f / (1.f + ex);
        float w1v = s + 1e-6f;                       // weight of i1
        float w2v = ex * s + 1e-6f;                  // weight of i2
        int ea = min(i1, i2), eb = max(i1, i2);
        float wa = (i1 < i2) ? w1v : w2v;
        float wb = (i1 < i2) ? w2v : w1v;
        wgt[tok * 2 + 0] = wa;
        wgt[tok * 2 + 1] = wb;
        int pid = ea * 7 - (ea * (ea - 1)) / 2 + (eb - ea - 1);
        int pos = atomicAdd(&pairCnt[pid], 1);
        bucket[pid * NTOK + pos] = tok;
    }
}

// ---------------- K2b: slot -> token map (scan 28 counts) ----------------
__global__ __launch_bounds__(256) void k_slots(const int* __restrict__ pairCnt,
                                               const int* __restrict__ bucket,
                                               int* __restrict__ tokmap) {
    int s = blockIdx.x * 256 + threadIdx.x;          // 8192 threads
    int off = 0;
    for (int p = 0; p < NPAIR; ++p) {
        int c = pairCnt[p];
        if (s < off + c) { tokmap[s] = bucket[p * NTOK + (s - off)]; return; }
        off += c;
    }
}

// ---- K2c: gather + bf16-pair pack: xg2p[(j*16+i2)][slot] = {bf16 x(i=2*i2), bf16 x(i=2*i2+1)} ----
__global__ __launch_bounds__(256) void k_xgp(const float* __restrict__ x,
                                             const int* __restrict__ tokmap,
                                             uint32_t* __restrict__ xg2p) {
    __shared__ float tile[64][65];
    int bs = blockIdx.x & 127, bd = blockIdx.x >> 7; // 128 s-tiles x 16 d-tiles; bd == i2
    int s0 = bs * 64, d0 = bd * 64;
    int tid = threadIdx.x;
    int sl = tid >> 2, q4 = tid & 3;
    int tok = tokmap[s0 + sl];
    const float* xr = x + (size_t)tok * DIM + d0 + q4 * 16;
    #pragma unroll
    for (int c = 0; c < 4; ++c) {
        float4 v = *(const float4*)&xr[c * 4];
        tile[sl][q4 * 16 + c * 4 + 0] = v.x;
        tile[sl][q4 * 16 + c * 4 + 1] = v.y;
        tile[sl][q4 * 16 + c * 4 + 2] = v.z;
        tile[sl][q4 * 16 + c * 4 + 3] = v.w;
    }
    __syncthreads();
    // d = i*32 + j; this d-tile holds i = {2*bd, 2*bd+1}, all j. tile col j -> i even, col j+32 -> i odd.
    int j = tid >> 3, q = tid & 7;
    uint32_t pk[8];
    #pragma unroll
    for (int s8 = 0; s8 < 8; ++s8) {
        int slot = q * 8 + s8;
        uint32_t lo = f2bf(tile[slot][j]);
        uint32_t hi = f2bf(tile[slot][j + 32]);
        pk[s8] = lo | (hi << 16);
    }
    uint32_t* orow = xg2p + (size_t)(j * 16 + bd) * NTOK + s0 + q * 8;
    uint4 v0, v1;
    v0.x = pk[0]; v0.y = pk[1]; v0.z = pk[2]; v0.w = pk[3];
    v1.x = pk[4]; v1.y = pk[5]; v1.z = pk[6]; v1.w = pk[7];
    *(uint4*)&orow[0] = v0;
    *(uint4*)&orow[4] = v1;
}

// ---------------- K3: fused BTT, 512 thr, double-buffered, coalesced epilogue ----------------
__global__ __launch_bounds__(512, 4) void k_main(const float* __restrict__ W2,
                                                 const float* __restrict__ bias,
                                                 const float* __restrict__ w1t2,
                                                 const uint32_t* __restrict__ xg2p,
                                                 const int* __restrict__ tokmap,
                                                 const float* __restrict__ wgt,
                                                 const int* __restrict__ pairCnt,
                                                 float* __restrict__ out) {
    // union: zs[2][8 j][2 e][2 h][64 t][4 f] fp32 (2x32KB)  |  ytr[64 t][4 k][64 l] fp32 (64KB)
    __shared__ float smem[16384];

    int bid = blockIdx.x;
    int kb = bid & 7, tb = bid >> 3;   // kb == XCD (round-robin dispatch) -> W1/W2 kb-slices L2-resident

    int p = -1, s0 = 0, cnt = 0;
    {
        int toff = 0, soff = 0;
        for (int q = 0; q < NPAIR; ++q) {
            int c = pairCnt[q];
            int nt = (c + 63) >> 6;
            if (p < 0 && tb < toff + nt) {
                int lt = tb - toff;
                p = q;
                s0 = soff + lt * 64;
                cnt = min(64, c - lt * 64);
            }
            toff += nt; soff += c;
        }
    }
    if (p < 0) return;
    p   = __builtin_amdgcn_readfirstlane(p);
    s0  = __builtin_amdgcn_readfirstlane(s0);
    cnt = __builtin_amdgcn_readfirstlane(cnt);

    int a = 0, r = p;
    while (r >= 7 - a) { r -= 7 - a; ++a; }
    int ea = a, eb = a + 1 + r;

    int tid = threadIdx.x, w = tid >> 6, lane = tid & 63;
    int sm = min(s0 + lane, NTOK - 1);
    int tok = tokmap[sm];
    float2 wv2 = *(const float2*)&wgt[tok * 2];
    float wsc[2] = { wv2.x, wv2.y };

    float y[8][8];
    #pragma unroll
    for (int kk = 0; kk < 8; ++kk)
        #pragma unroll
        for (int lt = 0; lt < 8; ++lt) y[kk][lt] = 0.f;

    // phase 1, chunk c -> buffer b: wave w computes j = c*8 + w; batched x loads (1 round-trip)
    auto phase1 = [&](int c, int b) {
        int jg = c * 8 + w;
        uint32_t xv[16];
        const uint32_t* xrow = xg2p + (size_t)jg * 16 * NTOK + sm;
        #pragma unroll
        for (int i2 = 0; i2 < 16; ++i2) xv[i2] = xrow[(size_t)i2 * NTOK];
        float acc[2][8];
        #pragma unroll
        for (int e = 0; e < 2; ++e)
            #pragma unroll
            for (int q = 0; q < 8; ++q) acc[e][q] = 0.f;
        const float* w1a = w1t2 + ((size_t)(kb * 8 + ea) * 32 + jg) * 256;
        const float* w1b = w1t2 + ((size_t)(kb * 8 + eb) * 32 + jg) * 256;
        #pragma unroll 4
        for (int i2 = 0; i2 < 16; ++i2) {
            float x0 = __uint_as_float(xv[i2] << 16);
            float x1 = __uint_as_float(xv[i2] & 0xffff0000u);
            const float* pa = w1a + i2 * 16;
            const float* pb = w1b + i2 * 16;
            float4 a0 = *(const float4*)(pa + 0);
            float4 a1 = *(const float4*)(pa + 4);
            float4 a2 = *(const float4*)(pa + 8);
            float4 a3 = *(const float4*)(pa + 12);
            acc[0][0] = fmaf(x0, a0.x, acc[0][0]); acc[0][1] = fmaf(x0, a0.y, acc[0][1]);
            acc[0][2] = fmaf(x0, a0.z, acc[0][2]); acc[0][3] = fmaf(x0, a0.w, acc[0][3]);
            acc[0][4] = fmaf(x0, a1.x, acc[0][4]); acc[0][5] = fmaf(x0, a1.y, acc[0][5]);
            acc[0][6] = fmaf(x0, a1.z, acc[0][6]); acc[0][7] = fmaf(x0, a1.w, acc[0][7]);
            acc[0][0] = fmaf(x1, a2.x, acc[0][0]); acc[0][1] = fmaf(x1, a2.y, acc[0][1]);
            acc[0][2] = fmaf(x1, a2.z, acc[0][2]); acc[0][3] = fmaf(x1, a2.w, acc[0][3]);
            acc[0][4] = fmaf(x1, a3.x, acc[0][4]); acc[0][5] = fmaf(x1, a3.y, acc[0][5]);
            acc[0][6] = fmaf(x1, a3.z, acc[0][6]); acc[0][7] = fmaf(x1, a3.w, acc[0][7]);
            float4 b0 = *(const float4*)(pb + 0);
            float4 b1 = *(const float4*)(pb + 4);
            float4 b2 = *(const float4*)(pb + 8);
            float4 b3 = *(const float4*)(pb + 12);
            acc[1][0] = fmaf(x0, b0.x, acc[1][0]); acc[1][1] = fmaf(x0, b0.y, acc[1][1]);
            acc[1][2] = fmaf(x0, b0.z, acc[1][2]); acc[1][3] = fmaf(x0, b0.w, acc[1][3]);
            acc[1][4] = fmaf(x0, b1.x, acc[1][4]); acc[1][5] = fmaf(x0, b1.y, acc[1][5]);
            acc[1][6] = fmaf(x0, b1.z, acc[1][6]); acc[1][7] = fmaf(x0, b1.w, acc[1][7]);
            acc[1][0] = fmaf(x1, b2.x, acc[1][0]); acc[1][1] = fmaf(x1, b2.y, acc[1][1]);
            acc[1][2] = fmaf(x1, b2.z, acc[1][2]); acc[1][3] = fmaf(x1, b2.w, acc[1][3]);
            acc[1][4] = fmaf(x1, b3.x, acc[1][4]); acc[1][5] = fmaf(x1, b3.y, acc[1][5]);
            acc[1][6] = fmaf(x1, b3.z, acc[1][6]); acc[1][7] = fmaf(x1, b3.w, acc[1][7]);
        }
        #pragma unroll
        for (int e = 0; e < 2; ++e) {
            float g = wsc[e];
            #pragma unroll
            for (int h = 0; h < 2; ++h) {
                float4 v;
                v.x = acc[e][h * 4 + 0] * g;
                v.y = acc[e][h * 4 + 1] * g;
                v.z = acc[e][h * 4 + 2] * g;
                v.w = acc[e][h * 4 + 3] * g;
                *(float4*)&smem[((((b * 8 + w) * 2 + e) * 2 + h) * 64 + lane) * 4] = v;
            }
        }
    };

    // phase 2, chunk c from buffer b: thread owns t=lane, l = w*8..w*8+8
    auto phase2 = [&](int c, int b) {
        #pragma unroll
        for (int je = 0; je < 16; ++je) {
            int j = je >> 1, e = je & 1;
            const float* zp = &smem[((((b * 8 + j) * 2 + e) * 2 + 0) * 64 + lane) * 4];
            float4 z0 = *(const float4*)zp;
            float4 z1 = *(const float4*)(zp + 256);      // h=1
            float zf[8];
            zf[0] = z0.x; zf[1] = z0.y; zf[2] = z0.z; zf[3] = z0.w;
            zf[4] = z1.x; zf[5] = z1.y; zf[6] = z1.z; zf[7] = z1.w;
            int eid = e ? eb : ea;
            const float* w2p = W2 + (((size_t)eid * 64 + kb * 8) * 32 + (c * 8 + j)) * 64 + w * 8;
            #pragma unroll
            for (int kk = 0; kk < 8; ++kk) {
                const float* wr = w2p + (size_t)kk * 2048;   // k stride = 32*64
                float4 u0 = *(const float4*)wr;
                float4 u1 = *(const float4*)(wr + 4);
                float z = zf[kk];
                y[kk][0] = fmaf(z, u0.x, y[kk][0]);
                y[kk][1] = fmaf(z, u0.y, y[kk][1]);
                y[kk][2] = fmaf(z, u0.z, y[kk][2]);
                y[kk][3] = fmaf(z, u0.w, y[kk][3]);
                y[kk][4] = fmaf(z, u1.x, y[kk][4]);
                y[kk][5] = fmaf(z, u1.y, y[kk][5]);
                y[kk][6] = fmaf(z, u1.z, y[kk][6]);
                y[kk][7] = fmaf(z, u1.w, y[kk][7]);
            }
        }
    };

    phase1(0, 0);
    __syncthreads();
    #pragma unroll
    for (int c = 0; c < 4; ++c) {
        if (c < 3) phase1(c + 1, (c + 1) & 1);
        phase2(c, c & 1);
        __syncthreads();
    }

    // ---- epilogue: LDS transpose -> coalesced stores (lane = output column) ----
    // ytr row t: 1024B = 64 x 16B chunks; chunk c = kq*16 + w*2 + hh, stored at (c ^ (t&7))
    #pragma unroll
    for (int h2 = 0; h2 < 2; ++h2) {
        #pragma unroll
        for (int kq = 0; kq < 4; ++kq) {
            int kk = h2 * 4 + kq;
            #pragma unroll
            for (int hh = 0; hh < 2; ++hh) {
                int cch = kq * 16 + w * 2 + hh;
                float4 v;
                v.x = y[kk][hh * 4 + 0];
                v.y = y[kk][hh * 4 + 1];
                v.z = y[kk][hh * 4 + 2];
                v.w = y[kk][hh * 4 + 3];
                *(float4*)((char*)smem + lane * 1024 + ((cch ^ (lane & 7)) << 4)) = v;
            }
        }
        __syncthreads();
        #pragma unroll
        for (int kq = 0; kq < 4; ++kq) {
            float bv = bias[(kb * 8 + h2 * 4 + kq) * 64 + lane];
            #pragma unroll
            for (int tt = 0; tt < 8; ++tt) {
                int t = w * 8 + tt;
                if (t < cnt) {
                    int tk = tokmap[s0 + t];
                    int cr = kq * 16 + (lane >> 2);
                    float v = *(const float*)((const char*)smem + t * 1024 +
                                              ((cr ^ (t & 7)) << 4) + (lane & 3) * 4);
                    out[(size_t)tk * OUTD + (size_t)(kb * 8 + h2 * 4 + kq) * 64 + lane] = v + bv;
                }
            }
        }
        if (h2 == 0) __syncthreads();
    }
}

extern "C" void kernel_launch(void* const* d_in, const int* in_sizes, int n_in,
                              void* d_out, int out_size, void* d_ws, size_t ws_size,
                              hipStream_t stream) {
    const float* x  = (const float*)d_in[0];
    const float* Wg = (const float*)d_in[1];
    const float* W1 = (const float*)d_in[2];
    const float* W2 = (const float*)d_in[3];
    const float* b  = (const float*)d_in[4];
    float* out = (float*)d_out;

    float*    w1t2   = (float*)d_ws;                         // 524288 f
    uint32_t* xg2p   = (uint32_t*)(w1t2 + 524288);           // 512*8192 u32 (bf16 pairs)
    int*      tokmap = (int*)(xg2p + (size_t)512 * NTOK);    // 8192 i
    float*    wgt    = (float*)(tokmap + NTOK);              // 16384 f
    int*      pairCnt = (int*)(wgt + 2 * NTOK);              // 32 i
    int*      bucket  = pairCnt + 32;                        // 28*8192 i

    hipMemsetAsync(pairCnt, 0, 32 * sizeof(int), stream);
    k_w1t2 <<<2048, 256, 0, stream>>>(W1, w1t2);
    k_gate <<<2048, 256, 0, stream>>>(x, Wg, pairCnt, bucket, wgt);
    k_slots<<<32,   256, 0, stream>>>(pairCnt, bucket, tokmap);
    k_xgp  <<<2048, 256, 0, stream>>>(x, tokmap, xg2p);
    k_main <<<MAXTILES * 8, 512, 0, stream>>>(W2, b, w1t2, xg2p, tokmap, wgt, pairCnt, out);
}

// Round 4
// 335.281 us; speedup vs baseline: 2.6111x; 2.0973x over previous
//
#include <hip/hip_runtime.h>
#include <stdint.h>

#define NTOK 8192
#define DIM  1024
#define NE   8
#define NPAIR 28
#define OUTD 4096
#define MAXTILES 155   // >= sum_p ceil(cnt_p/64) worst case (128 + 27)

static __device__ __forceinline__ unsigned short f2bf(float f) {
    uint32_t u = __float_as_uint(f);
    u += 0x7fffu + ((u >> 16) & 1u);     // RNE
    return (unsigned short)(u >> 16);
}

// ---------------- K0: W1[j][i][k][e] -> w1t2[kb][e][j][i][kk] ----------------
__global__ __launch_bounds__(256) void k_w1t2(const float* __restrict__ W1,
                                              float* __restrict__ w1t2) {
    int t = blockIdx.x * 256 + threadIdx.x;          // 524288 total
    int kk = t & 7, i = (t >> 3) & 31, j = (t >> 8) & 31, e = (t >> 13) & 7, kb = (t >> 16) & 7;
    w1t2[t] = W1[(((j * 32 + i) * 64) + kb * 8 + kk) * 8 + e];
}

// ---------------- K1: gate (fp32) + pair bucketing ----------------
__global__ __launch_bounds__(256) void k_gate(const float* __restrict__ x,
                                              const float* __restrict__ Wg,
                                              int* __restrict__ pairCnt,
                                              int* __restrict__ bucket,
                                              float* __restrict__ wgt) {
    __shared__ float sWg[NE][DIM];                   // 32 KB
    int tid = threadIdx.x;
    #pragma unroll
    for (int u = 0; u < 8; ++u) {
        int idx = u * 1024 + tid * 4;
        *(float4*)&sWg[0][idx] = *(const float4*)&Wg[idx];
    }
    __syncthreads();
    int w = tid >> 6, lane = tid & 63;
    int tok = blockIdx.x * 4 + w;
    float acc[NE];
    #pragma unroll
    for (int e = 0; e < NE; ++e) acc[e] = 0.f;
    const float* xr = x + (size_t)tok * DIM;
    #pragma unroll
    for (int c = 0; c < 4; ++c) {
        float4 xv = *(const float4*)&xr[c * 256 + lane * 4];
        #pragma unroll
        for (int e = 0; e < NE; ++e) {
            float4 wv = *(const float4*)&sWg[e][c * 256 + lane * 4];
            acc[e] += xv.x * wv.x + xv.y * wv.y + xv.z * wv.z + xv.w * wv.w;
        }
    }
    #pragma unroll
    for (int e = 0; e < NE; ++e)
        #pragma unroll
        for (int off = 32; off > 0; off >>= 1)
            acc[e] += __shfl_xor(acc[e], off, 64);
    if (lane == 0) {
        int i1 = 0; float v1 = acc[0];
        for (int e = 1; e < NE; ++e) if (acc[e] > v1) { v1 = acc[e]; i1 = e; }
        int i2 = -1; float v2 = -3.4e38f;
        for (int e = 0; e < NE; ++e) { if (e == i1) continue; if (acc[e] > v2) { v2 = acc[e]; i2 = e; } }
        float ex = expf(v2 - v1);                    // v2 <= v1
        float s  = 1.f / (1.f + ex);
        float w1v = s + 1e-6f;                       // weight of i1
        float w2v = ex * s + 1e-6f;                  // weight of i2
        int ea = min(i1, i2), eb = max(i1, i2);
        float wa = (i1 < i2) ? w1v : w2v;
        float wb = (i1 < i2) ? w2v : w1v;
        wgt[tok * 2 + 0] = wa;
        wgt[tok * 2 + 1] = wb;
        int pid = ea * 7 - (ea * (ea - 1)) / 2 + (eb - ea - 1);
        int pos = atomicAdd(&pairCnt[pid], 1);
        bucket[pid * NTOK + pos] = tok;
    }
}

// ---------------- K2b: slot -> token map (scan 28 counts) ----------------
__global__ __launch_bounds__(256) void k_slots(const int* __restrict__ pairCnt,
                                               const int* __restrict__ bucket,
                                               int* __restrict__ tokmap) {
    int s = blockIdx.x * 256 + threadIdx.x;          // 8192 threads
    int off = 0;
    for (int p = 0; p < NPAIR; ++p) {
        int c = pairCnt[p];
        if (s < off + c) { tokmap[s] = bucket[p * NTOK + (s - off)]; return; }
        off += c;
    }
}

// ---- K2c: gather + bf16-pair pack: xg2p[(j*16+i2)][slot] = {bf16 x(i=2*i2), bf16 x(i=2*i2+1)} ----
__global__ __launch_bounds__(256) void k_xgp(const float* __restrict__ x,
                                             const int* __restrict__ tokmap,
                                             uint32_t* __restrict__ xg2p) {
    __shared__ float tile[64][65];
    int bs = blockIdx.x & 127, bd = blockIdx.x >> 7; // 128 s-tiles x 16 d-tiles; bd == i2
    int s0 = bs * 64, d0 = bd * 64;
    int tid = threadIdx.x;
    int sl = tid >> 2, q4 = tid & 3;
    int tok = tokmap[s0 + sl];
    const float* xr = x + (size_t)tok * DIM + d0 + q4 * 16;
    #pragma unroll
    for (int c = 0; c < 4; ++c) {
        float4 v = *(const float4*)&xr[c * 4];
        tile[sl][q4 * 16 + c * 4 + 0] = v.x;
        tile[sl][q4 * 16 + c * 4 + 1] = v.y;
        tile[sl][q4 * 16 + c * 4 + 2] = v.z;
        tile[sl][q4 * 16 + c * 4 + 3] = v.w;
    }
    __syncthreads();
    // d = i*32 + j; this d-tile holds i = {2*bd, 2*bd+1}, all j. col j -> i even, col j+32 -> i odd.
    int j = tid >> 3, q = tid & 7;
    uint32_t pk[8];
    #pragma unroll
    for (int s8 = 0; s8 < 8; ++s8) {
        int slot = q * 8 + s8;
        uint32_t lo = f2bf(tile[slot][j]);
        uint32_t hi = f2bf(tile[slot][j + 32]);
        pk[s8] = lo | (hi << 16);
    }
    uint32_t* orow = xg2p + (size_t)(j * 16 + bd) * NTOK + s0 + q * 8;
    uint4 v0, v1;
    v0.x = pk[0]; v0.y = pk[1]; v0.z = pk[2]; v0.w = pk[3];
    v1.x = pk[4]; v1.y = pk[5]; v1.z = pk[6]; v1.w = pk[7];
    *(uint4*)&orow[0] = v0;
    *(uint4*)&orow[4] = v1;
}

// helper: tile scan (tb -> pair p, slot base s0, count cnt)
static __device__ __forceinline__ bool tile_scan(const int* __restrict__ pairCnt,
                                                 int tb, int& p, int& s0, int& cnt) {
    p = -1; s0 = 0; cnt = 0;
    int toff = 0, soff = 0;
    for (int q = 0; q < NPAIR; ++q) {
        int c = pairCnt[q];
        int nt = (c + 63) >> 6;
        if (p < 0 && tb < toff + nt) {
            int lt = tb - toff;
            p = q;
            s0 = soff + lt * 64;
            cnt = min(64, c - lt * 64);
        }
        toff += nt; soff += c;
    }
    return p >= 0;
}

// ---------------- K3: z[(j*2+e)*16 + k2loc][slot] (bf16 k-pairs), gate-scaled ----------------
// pass h covers kb = h*4 .. h*4+3 (global k = h*32 .. h*32+31)
__global__ __launch_bounds__(512) void k_z(const float* __restrict__ w1t2,
                                           const uint32_t* __restrict__ xg2p,
                                           const int* __restrict__ tokmap,
                                           const float* __restrict__ wgt,
                                           const int* __restrict__ pairCnt,
                                           uint32_t* __restrict__ zbuf,
                                           int h) {
    int bid = blockIdx.x;
    int kbl = bid & 3, tb = bid >> 2;
    int kb = h * 4 + kbl;

    int p, s0, cnt;
    if (!tile_scan(pairCnt, tb, p, s0, cnt)) return;
    p   = __builtin_amdgcn_readfirstlane(p);
    s0  = __builtin_amdgcn_readfirstlane(s0);
    cnt = __builtin_amdgcn_readfirstlane(cnt);

    int a = 0, r = p;
    while (r >= 7 - a) { r -= 7 - a; ++a; }
    int ea = a, eb = a + 1 + r;

    int tid = threadIdx.x;
    int wu = __builtin_amdgcn_readfirstlane(tid >> 6);
    int lane = tid & 63;
    int sm = min(s0 + lane, NTOK - 1);
    bool valid = lane < cnt;
    int tok = tokmap[sm];
    float2 wv2 = *(const float2*)&wgt[tok * 2];
    float wsc[2] = { wv2.x, wv2.y };

    for (int cj = 0; cj < 4; ++cj) {
        int jg = cj * 8 + wu;
        const uint32_t* xrow = xg2p + (size_t)jg * 16 * NTOK + sm;
        uint32_t xv[16];
        #pragma unroll
        for (int i2 = 0; i2 < 16; ++i2) xv[i2] = xrow[(size_t)i2 * NTOK];

        float acc[2][8];
        #pragma unroll
        for (int e = 0; e < 2; ++e)
            #pragma unroll
            for (int q = 0; q < 8; ++q) acc[e][q] = 0.f;

        const float* w1a = w1t2 + ((size_t)(kb * 8 + ea) * 32 + jg) * 256;
        const float* w1b = w1t2 + ((size_t)(kb * 8 + eb) * 32 + jg) * 256;
        #pragma unroll 4
        for (int i2 = 0; i2 < 16; ++i2) {
            float x0 = __uint_as_float(xv[i2] << 16);
            float x1 = __uint_as_float(xv[i2] & 0xffff0000u);
            const float* pa = w1a + i2 * 16;
            const float* pb = w1b + i2 * 16;
            float4 a0 = *(const float4*)(pa + 0);
            float4 a1 = *(const float4*)(pa + 4);
            float4 a2 = *(const float4*)(pa + 8);
            float4 a3 = *(const float4*)(pa + 12);
            acc[0][0] = fmaf(x0, a0.x, acc[0][0]); acc[0][1] = fmaf(x0, a0.y, acc[0][1]);
            acc[0][2] = fmaf(x0, a0.z, acc[0][2]); acc[0][3] = fmaf(x0, a0.w, acc[0][3]);
            acc[0][4] = fmaf(x0, a1.x, acc[0][4]); acc[0][5] = fmaf(x0, a1.y, acc[0][5]);
            acc[0][6] = fmaf(x0, a1.z, acc[0][6]); acc[0][7] = fmaf(x0, a1.w, acc[0][7]);
            acc[0][0] = fmaf(x1, a2.x, acc[0][0]); acc[0][1] = fmaf(x1, a2.y, acc[0][1]);
            acc[0][2] = fmaf(x1, a2.z, acc[0][2]); acc[0][3] = fmaf(x1, a2.w, acc[0][3]);
            acc[0][4] = fmaf(x1, a3.x, acc[0][4]); acc[0][5] = fmaf(x1, a3.y, acc[0][5]);
            acc[0][6] = fmaf(x1, a3.z, acc[0][6]); acc[0][7] = fmaf(x1, a3.w, acc[0][7]);
            float4 b0 = *(const float4*)(pb + 0);
            float4 b1 = *(const float4*)(pb + 4);
            float4 b2 = *(const float4*)(pb + 8);
            float4 b3 = *(const float4*)(pb + 12);
            acc[1][0] = fmaf(x0, b0.x, acc[1][0]); acc[1][1] = fmaf(x0, b0.y, acc[1][1]);
            acc[1][2] = fmaf(x0, b0.z, acc[1][2]); acc[1][3] = fmaf(x0, b0.w, acc[1][3]);
            acc[1][4] = fmaf(x0, b1.x, acc[1][4]); acc[1][5] = fmaf(x0, b1.y, acc[1][5]);
            acc[1][6] = fmaf(x0, b1.z, acc[1][6]); acc[1][7] = fmaf(x0, b1.w, acc[1][7]);
            acc[1][0] = fmaf(x1, b2.x, acc[1][0]); acc[1][1] = fmaf(x1, b2.y, acc[1][1]);
            acc[1][2] = fmaf(x1, b2.z, acc[1][2]); acc[1][3] = fmaf(x1, b2.w, acc[1][3]);
            acc[1][4] = fmaf(x1, b3.x, acc[1][4]); acc[1][5] = fmaf(x1, b3.y, acc[1][5]);
            acc[1][6] = fmaf(x1, b3.z, acc[1][6]); acc[1][7] = fmaf(x1, b3.w, acc[1][7]);
        }
        #pragma unroll
        for (int e = 0; e < 2; ++e) {
            float g = wsc[e];
            #pragma unroll
            for (int kq = 0; kq < 4; ++kq) {
                uint32_t pk = (uint32_t)f2bf(acc[e][kq * 2 + 0] * g) |
                              ((uint32_t)f2bf(acc[e][kq * 2 + 1] * g) << 16);
                if (valid)
                    zbuf[(size_t)((jg * 2 + e) * 16 + kbl * 4 + kq) * NTOK + sm] = pk;
            }
        }
    }
}

// ---------------- K4: y — lane = output column, z via wave-uniform loads ----------------
// pass h: block ksl covers global k = h*32 + ksl*4 .. +3  (k2 local rows ksl*2, ksl*2+1)
__global__ __launch_bounds__(512) void k_y(const float* __restrict__ W2,
                                           const float* __restrict__ bias,
                                           const uint32_t* __restrict__ zbuf,
                                           const int* __restrict__ tokmap,
                                           const int* __restrict__ pairCnt,
                                           float* __restrict__ out,
                                           int h) {
    int bid = blockIdx.x;
    int ksl = bid & 7, tb = bid >> 3;

    int p, s0, cnt;
    if (!tile_scan(pairCnt, tb, p, s0, cnt)) return;
    p   = __builtin_amdgcn_readfirstlane(p);
    s0  = __builtin_amdgcn_readfirstlane(s0);
    cnt = __builtin_amdgcn_readfirstlane(cnt);

    int a = 0, r = p;
    while (r >= 7 - a) { r -= 7 - a; ++a; }
    int ea = a, eb = a + 1 + r;

    int tid = threadIdx.x;
    int wu = __builtin_amdgcn_readfirstlane(tid >> 6);
    int lane = tid & 63;
    int kbase = h * 32 + ksl * 4;

    float y[8][4];
    #pragma unroll
    for (int tt = 0; tt < 8; ++tt)
        #pragma unroll
        for (int kk = 0; kk < 4; ++kk) y[tt][kk] = 0.f;

    int zoff = s0 + wu * 8;                          // wave-uniform slot base

    for (int j = 0; j < 32; ++j) {
        #pragma unroll
        for (int e = 0; e < 2; ++e) {
            int eid = e ? eb : ea;
            // coalesced W2 rows: lanes read consecutive l for each of the 4 k
            const float* w2p = W2 + (((size_t)eid * 64 + kbase) * 32 + j) * 64 + lane;
            float w0 = w2p[0];
            float w1 = w2p[2048];
            float w2 = w2p[4096];
            float w3 = w2p[6144];
            // wave-uniform z loads: rows (j*2+e)*16 + ksl*2 (+1), 8 tokens each
            const uint32_t* zA = zbuf + (size_t)((j * 2 + e) * 16 + ksl * 2) * NTOK + zoff;
            const uint32_t* zB = zA + NTOK;
            uint32_t za[8], zb[8];
            #pragma unroll
            for (int q = 0; q < 8; ++q) { za[q] = zA[q]; zb[q] = zB[q]; }
            #pragma unroll
            for (int tt = 0; tt < 8; ++tt) {
                float zA0 = __uint_as_float(za[tt] << 16);
                float zA1 = __uint_as_float(za[tt] & 0xffff0000u);
                float zB0 = __uint_as_float(zb[tt] << 16);
                float zB1 = __uint_as_float(zb[tt] & 0xffff0000u);
                y[tt][0] = fmaf(zA0, w0, y[tt][0]);
                y[tt][1] = fmaf(zA1, w1, y[tt][1]);
                y[tt][2] = fmaf(zB0, w2, y[tt][2]);
                y[tt][3] = fmaf(zB1, w3, y[tt][3]);
            }
        }
    }

    float bv[4];
    #pragma unroll
    for (int kk = 0; kk < 4; ++kk) bv[kk] = bias[(kbase + kk) * 64 + lane];

    #pragma unroll
    for (int tt = 0; tt < 8; ++tt) {
        int t = wu * 8 + tt;
        if (t < cnt) {
            int tk = tokmap[s0 + t];
            float* orow = out + (size_t)tk * OUTD + (size_t)kbase * 64 + lane;
            #pragma unroll
            for (int kk = 0; kk < 4; ++kk)
                __builtin_nontemporal_store(y[tt][kk] + bv[kk], orow + (size_t)kk * 64);
        }
    }
}

extern "C" void kernel_launch(void* const* d_in, const int* in_sizes, int n_in,
                              void* d_out, int out_size, void* d_ws, size_t ws_size,
                              hipStream_t stream) {
    const float* x  = (const float*)d_in[0];
    const float* Wg = (const float*)d_in[1];
    const float* W1 = (const float*)d_in[2];
    const float* W2 = (const float*)d_in[3];
    const float* b  = (const float*)d_in[4];
    float* out = (float*)d_out;

    float*    w1t2   = (float*)d_ws;                          // 524288 f   (2 MB)
    uint32_t* xg2p   = (uint32_t*)(w1t2 + 524288);            // 512*8192 u32 (16 MB)
    uint32_t* zbuf   = xg2p + (size_t)512 * NTOK;             // 1024*8192 u32 (32 MB)
    int*      tokmap = (int*)(zbuf + (size_t)1024 * NTOK);    // 8192 i
    float*    wgt    = (float*)(tokmap + NTOK);               // 16384 f
    int*      pairCnt = (int*)(wgt + 2 * NTOK);               // 32 i
    int*      bucket  = pairCnt + 32;                         // 28*8192 i

    hipMemsetAsync(pairCnt, 0, 32 * sizeof(int), stream);
    k_w1t2 <<<2048, 256, 0, stream>>>(W1, w1t2);
    k_gate <<<2048, 256, 0, stream>>>(x, Wg, pairCnt, bucket, wgt);
    k_slots<<<32,   256, 0, stream>>>(pairCnt, bucket, tokmap);
    k_xgp  <<<2048, 256, 0, stream>>>(x, tokmap, xg2p);
    for (int h = 0; h < 2; ++h) {
        k_z<<<MAXTILES * 4, 512, 0, stream>>>(w1t2, xg2p, tokmap, wgt, pairCnt, zbuf, h);
        k_y<<<MAXTILES * 8, 512, 0, stream>>>(W2, b, zbuf, tokmap, pairCnt, out, h);
    }
}

// Round 5
// 304.229 us; speedup vs baseline: 2.8776x; 1.1021x over previous
//
#include <hip/hip_runtime.h>
#include <stdint.h>

#define NTOK 8192
#define DIM  1024
#define NE   8
#define NPAIR 28
#define OUTD 4096
#define MAXTILES 155   // >= sum_p ceil(cnt_p/64) worst case (128 + 27)

static __device__ __forceinline__ unsigned short f2bf(float f) {
    uint32_t u = __float_as_uint(f);
    u += 0x7fffu + ((u >> 16) & 1u);     // RNE
    return (unsigned short)(u >> 16);
}

// ---------------- K0: W1[j][i][k][e] -> w1t2[kb][e][j][i][kk] ----------------
__global__ __launch_bounds__(256) void k_w1t2(const float* __restrict__ W1,
                                              float* __restrict__ w1t2) {
    int t = blockIdx.x * 256 + threadIdx.x;          // 524288 total
    int kk = t & 7, i = (t >> 3) & 31, j = (t >> 8) & 31, e = (t >> 13) & 7, kb = (t >> 16) & 7;
    w1t2[t] = W1[(((j * 32 + i) * 64) + kb * 8 + kk) * 8 + e];
}

// ---------------- K1: gate (fp32) + pair bucketing ----------------
__global__ __launch_bounds__(256) void k_gate(const float* __restrict__ x,
                                              const float* __restrict__ Wg,
                                              int* __restrict__ pairCnt,
                                              int* __restrict__ bucket,
                                              float* __restrict__ wgt) {
    __shared__ float sWg[NE][DIM];                   // 32 KB
    int tid = threadIdx.x;
    #pragma unroll
    for (int u = 0; u < 8; ++u) {
        int idx = u * 1024 + tid * 4;
        *(float4*)&sWg[0][idx] = *(const float4*)&Wg[idx];
    }
    __syncthreads();
    int w = tid >> 6, lane = tid & 63;
    int tok = blockIdx.x * 4 + w;
    float acc[NE];
    #pragma unroll
    for (int e = 0; e < NE; ++e) acc[e] = 0.f;
    const float* xr = x + (size_t)tok * DIM;
    #pragma unroll
    for (int c = 0; c < 4; ++c) {
        float4 xv = *(const float4*)&xr[c * 256 + lane * 4];
        #pragma unroll
        for (int e = 0; e < NE; ++e) {
            float4 wv = *(const float4*)&sWg[e][c * 256 + lane * 4];
            acc[e] += xv.x * wv.x + xv.y * wv.y + xv.z * wv.z + xv.w * wv.w;
        }
    }
    #pragma unroll
    for (int e = 0; e < NE; ++e)
        #pragma unroll
        for (int off = 32; off > 0; off >>= 1)
            acc[e] += __shfl_xor(acc[e], off, 64);
    if (lane == 0) {
        int i1 = 0; float v1 = acc[0];
        for (int e = 1; e < NE; ++e) if (acc[e] > v1) { v1 = acc[e]; i1 = e; }
        int i2 = -1; float v2 = -3.4e38f;
        for (int e = 0; e < NE; ++e) { if (e == i1) continue; if (acc[e] > v2) { v2 = acc[e]; i2 = e; } }
        float ex = expf(v2 - v1);                    // v2 <= v1
        float s  = 1.f / (1.f + ex);
        float w1v = s + 1e-6f;                       // weight of i1
        float w2v = ex * s + 1e-6f;                  // weight of i2
        int ea = min(i1, i2), eb = max(i1, i2);
        float wa = (i1 < i2) ? w1v : w2v;
        float wb = (i1 < i2) ? w2v : w1v;
        wgt[tok * 2 + 0] = wa;
        wgt[tok * 2 + 1] = wb;
        int pid = ea * 7 - (ea * (ea - 1)) / 2 + (eb - ea - 1);
        int pos = atomicAdd(&pairCnt[pid], 1);
        bucket[pid * NTOK + pos] = tok;
    }
}

// ---------------- K2b: slot -> token map (scan 28 counts) ----------------
__global__ __launch_bounds__(256) void k_slots(const int* __restrict__ pairCnt,
                                               const int* __restrict__ bucket,
                                               int* __restrict__ tokmap) {
    int s = blockIdx.x * 256 + threadIdx.x;          // 8192 threads
    int off = 0;
    for (int p = 0; p < NPAIR; ++p) {
        int c = pairCnt[p];
        if (s < off + c) { tokmap[s] = bucket[p * NTOK + (s - off)]; return; }
        off += c;
    }
}

// ---- K2c: gather + bf16-pair pack: xg2p[(j*16+i2)][slot] = {bf16 x(i=2*i2), bf16 x(i=2*i2+1)} ----
__global__ __launch_bounds__(256) void k_xgp(const float* __restrict__ x,
                                             const int* __restrict__ tokmap,
                                             uint32_t* __restrict__ xg2p) {
    __shared__ float tile[64][65];
    int bs = blockIdx.x & 127, bd = blockIdx.x >> 7; // 128 s-tiles x 16 d-tiles; bd == i2
    int s0 = bs * 64, d0 = bd * 64;
    int tid = threadIdx.x;
    int sl = tid >> 2, q4 = tid & 3;
    int tok = tokmap[s0 + sl];
    const float* xr = x + (size_t)tok * DIM + d0 + q4 * 16;
    #pragma unroll
    for (int c = 0; c < 4; ++c) {
        float4 v = *(const float4*)&xr[c * 4];
        tile[sl][q4 * 16 + c * 4 + 0] = v.x;
        tile[sl][q4 * 16 + c * 4 + 1] = v.y;
        tile[sl][q4 * 16 + c * 4 + 2] = v.z;
        tile[sl][q4 * 16 + c * 4 + 3] = v.w;
    }
    __syncthreads();
    // d = i*32 + j; this d-tile holds i = {2*bd, 2*bd+1}, all j. col j -> i even, col j+32 -> i odd.
    int j = tid >> 3, q = tid & 7;
    uint32_t pk[8];
    #pragma unroll
    for (int s8 = 0; s8 < 8; ++s8) {
        int slot = q * 8 + s8;
        uint32_t lo = f2bf(tile[slot][j]);
        uint32_t hi = f2bf(tile[slot][j + 32]);
        pk[s8] = lo | (hi << 16);
    }
    uint32_t* orow = xg2p + (size_t)(j * 16 + bd) * NTOK + s0 + q * 8;
    uint4 v0, v1;
    v0.x = pk[0]; v0.y = pk[1]; v0.z = pk[2]; v0.w = pk[3];
    v1.x = pk[4]; v1.y = pk[5]; v1.z = pk[6]; v1.w = pk[7];
    *(uint4*)&orow[0] = v0;
    *(uint4*)&orow[4] = v1;
}

// helper: tile scan (tb -> pair p, slot base s0, count cnt)
static __device__ __forceinline__ bool tile_scan(const int* __restrict__ pairCnt,
                                                 int tb, int& p, int& s0, int& cnt) {
    p = -1; s0 = 0; cnt = 0;
    int toff = 0, soff = 0;
    for (int q = 0; q < NPAIR; ++q) {
        int c = pairCnt[q];
        int nt = (c + 63) >> 6;
        if (p < 0 && tb < toff + nt) {
            int lt = tb - toff;
            p = q;
            s0 = soff + lt * 64;
            cnt = min(64, c - lt * 64);
        }
        toff += nt; soff += c;
    }
    return p >= 0;
}

// ---------------- K3: z[(j*2+e)*Q + (kb-kb0)*4 + kq][slot] (bf16 k-pairs), gate-scaled ----------------
__global__ __launch_bounds__(512) void k_z(const float* __restrict__ w1t2,
                                           const uint32_t* __restrict__ xg2p,
                                           const int* __restrict__ tokmap,
                                           const float* __restrict__ wgt,
                                           const int* __restrict__ pairCnt,
                                           uint32_t* __restrict__ zbuf,
                                           int kb0, int Q) {
    int nkbl = Q >> 2;
    int bid = blockIdx.x;
    int kbl = bid % nkbl, tb = bid / nkbl;
    int kb = kb0 + kbl;

    int p, s0, cnt;
    if (!tile_scan(pairCnt, tb, p, s0, cnt)) return;
    p   = __builtin_amdgcn_readfirstlane(p);
    s0  = __builtin_amdgcn_readfirstlane(s0);
    cnt = __builtin_amdgcn_readfirstlane(cnt);

    int a = 0, r = p;
    while (r >= 7 - a) { r -= 7 - a; ++a; }
    int ea = a, eb = a + 1 + r;

    int tid = threadIdx.x;
    int wu = __builtin_amdgcn_readfirstlane(tid >> 6);
    int lane = tid & 63;
    int sm = min(s0 + lane, NTOK - 1);
    bool valid = lane < cnt;
    int tok = tokmap[sm];
    float2 wv2 = *(const float2*)&wgt[tok * 2];
    float wsc[2] = { wv2.x, wv2.y };

    // ---- prefetch ALL x for this block (64 u32 regs): one latency wall ----
    uint32_t xall[4][16];
    #pragma unroll
    for (int cj = 0; cj < 4; ++cj) {
        const uint32_t* xrow = xg2p + (size_t)((cj * 8 + wu) * 16) * NTOK + sm;
        #pragma unroll
        for (int i2 = 0; i2 < 16; ++i2) xall[cj][i2] = xrow[(size_t)i2 * NTOK];
    }

    #pragma unroll
    for (int cj = 0; cj < 4; ++cj) {
        int jg = cj * 8 + wu;
        float acc[2][8];
        #pragma unroll
        for (int e = 0; e < 2; ++e)
            #pragma unroll
            for (int q = 0; q < 8; ++q) acc[e][q] = 0.f;

        const float* w1a = w1t2 + ((size_t)(kb * 8 + ea) * 32 + jg) * 256;
        const float* w1b = w1t2 + ((size_t)(kb * 8 + eb) * 32 + jg) * 256;
        #pragma unroll 4
        for (int i2 = 0; i2 < 16; ++i2) {
            float x0 = __uint_as_float(xall[cj][i2] << 16);
            float x1 = __uint_as_float(xall[cj][i2] & 0xffff0000u);
            const float* pa = w1a + i2 * 16;
            const float* pb = w1b + i2 * 16;
            float4 a0 = *(const float4*)(pa + 0);
            float4 a1 = *(const float4*)(pa + 4);
            float4 a2 = *(const float4*)(pa + 8);
            float4 a3 = *(const float4*)(pa + 12);
            acc[0][0] = fmaf(x0, a0.x, acc[0][0]); acc[0][1] = fmaf(x0, a0.y, acc[0][1]);
            acc[0][2] = fmaf(x0, a0.z, acc[0][2]); acc[0][3] = fmaf(x0, a0.w, acc[0][3]);
            acc[0][4] = fmaf(x0, a1.x, acc[0][4]); acc[0][5] = fmaf(x0, a1.y, acc[0][5]);
            acc[0][6] = fmaf(x0, a1.z, acc[0][6]); acc[0][7] = fmaf(x0, a1.w, acc[0][7]);
            acc[0][0] = fmaf(x1, a2.x, acc[0][0]); acc[0][1] = fmaf(x1, a2.y, acc[0][1]);
            acc[0][2] = fmaf(x1, a2.z, acc[0][2]); acc[0][3] = fmaf(x1, a2.w, acc[0][3]);
            acc[0][4] = fmaf(x1, a3.x, acc[0][4]); acc[0][5] = fmaf(x1, a3.y, acc[0][5]);
            acc[0][6] = fmaf(x1, a3.z, acc[0][6]); acc[0][7] = fmaf(x1, a3.w, acc[0][7]);
            float4 b0 = *(const float4*)(pb + 0);
            float4 b1 = *(const float4*)(pb + 4);
            float4 b2 = *(const float4*)(pb + 8);
            float4 b3 = *(const float4*)(pb + 12);
            acc[1][0] = fmaf(x0, b0.x, acc[1][0]); acc[1][1] = fmaf(x0, b0.y, acc[1][1]);
            acc[1][2] = fmaf(x0, b0.z, acc[1][2]); acc[1][3] = fmaf(x0, b0.w, acc[1][3]);
            acc[1][4] = fmaf(x0, b1.x, acc[1][4]); acc[1][5] = fmaf(x0, b1.y, acc[1][5]);
            acc[1][6] = fmaf(x0, b1.z, acc[1][6]); acc[1][7] = fmaf(x0, b1.w, acc[1][7]);
            acc[1][0] = fmaf(x1, b2.x, acc[1][0]); acc[1][1] = fmaf(x1, b2.y, acc[1][1]);
            acc[1][2] = fmaf(x1, b2.z, acc[1][2]); acc[1][3] = fmaf(x1, b2.w, acc[1][3]);
            acc[1][4] = fmaf(x1, b3.x, acc[1][4]); acc[1][5] = fmaf(x1, b3.y, acc[1][5]);
            acc[1][6] = fmaf(x1, b3.z, acc[1][6]); acc[1][7] = fmaf(x1, b3.w, acc[1][7]);
        }
        #pragma unroll
        for (int e = 0; e < 2; ++e) {
            float g = wsc[e];
            #pragma unroll
            for (int kq = 0; kq < 4; ++kq) {
                uint32_t pk = (uint32_t)f2bf(acc[e][kq * 2 + 0] * g) |
                              ((uint32_t)f2bf(acc[e][kq * 2 + 1] * g) << 16);
                if (valid)
                    zbuf[(size_t)((jg * 2 + e) * Q + kbl * 4 + kq) * NTOK + sm] = pk;
            }
        }
    }
}

// ---------------- K4: y — lane = output column, z staged in LDS ----------------
__global__ __launch_bounds__(512) void k_y(const float* __restrict__ W2,
                                           const float* __restrict__ bias,
                                           const uint32_t* __restrict__ zbuf,
                                           const int* __restrict__ tokmap,
                                           const int* __restrict__ pairCnt,
                                           float* __restrict__ out,
                                           int kb0, int Q) {
    __shared__ uint32_t zls[128][64];                // 32 KB: [(j*2+e)*2 + q][slot]
    int nksl = Q >> 1;
    int bid = blockIdx.x;
    int ksl = bid % nksl, tb = bid / nksl;

    int p, s0, cnt;
    if (!tile_scan(pairCnt, tb, p, s0, cnt)) return;
    p   = __builtin_amdgcn_readfirstlane(p);
    s0  = __builtin_amdgcn_readfirstlane(s0);
    cnt = __builtin_amdgcn_readfirstlane(cnt);

    int a = 0, r0 = p;
    while (r0 >= 7 - a) { r0 -= 7 - a; ++a; }
    int ea = a, eb = a + 1 + r0;

    int tid = threadIdx.x;
    int wraw = tid >> 6;
    int wu = __builtin_amdgcn_readfirstlane(wraw);
    int lane = tid & 63;
    int kbase = kb0 * 8 + ksl * 4;

    // ---- stage z: 128 rows x 64 slots, coalesced (one wave per row) ----
    #pragma unroll
    for (int s = 0; s < 16; ++s) {
        int rr = s * 8 + wraw;                       // 0..127
        int je = rr >> 1, q = rr & 1;
        zls[rr][lane] = zbuf[(size_t)(je * Q + ksl * 2 + q) * NTOK + s0 + lane];
    }
    __syncthreads();

    float y[8][4];
    #pragma unroll
    for (int tt = 0; tt < 8; ++tt)
        #pragma unroll
        for (int kk = 0; kk < 4; ++kk) y[tt][kk] = 0.f;

    int zo = wu * 8;

    #pragma unroll 2
    for (int j = 0; j < 32; ++j) {
        #pragma unroll
        for (int e = 0; e < 2; ++e) {
            int eid = e ? eb : ea;
            const float* w2p = W2 + (((size_t)eid * 64 + kbase) * 32 + j) * 64 + lane;
            float w0  = w2p[0];
            float w1v = w2p[2048];
            float w2v = w2p[4096];
            float w3v = w2p[6144];
            int rr = (j * 2 + e) * 2;
            uint4 a0 = *(const uint4*)&zls[rr][zo];
            uint4 a1 = *(const uint4*)&zls[rr][zo + 4];
            uint4 b0 = *(const uint4*)&zls[rr + 1][zo];
            uint4 b1 = *(const uint4*)&zls[rr + 1][zo + 4];
            auto step = [&](uint32_t ua, uint32_t ub, int tt) {
                y[tt][0] = fmaf(__uint_as_float(ua << 16),          w0,  y[tt][0]);
                y[tt][1] = fmaf(__uint_as_float(ua & 0xffff0000u),  w1v, y[tt][1]);
                y[tt][2] = fmaf(__uint_as_float(ub << 16),          w2v, y[tt][2]);
                y[tt][3] = fmaf(__uint_as_float(ub & 0xffff0000u),  w3v, y[tt][3]);
            };
            step(a0.x, b0.x, 0); step(a0.y, b0.y, 1);
            step(a0.z, b0.z, 2); step(a0.w, b0.w, 3);
            step(a1.x, b1.x, 4); step(a1.y, b1.y, 5);
            step(a1.z, b1.z, 6); step(a1.w, b1.w, 7);
        }
    }

    float bv[4];
    #pragma unroll
    for (int kk = 0; kk < 4; ++kk) bv[kk] = bias[(kbase + kk) * 64 + lane];

    #pragma unroll
    for (int tt = 0; tt < 8; ++tt) {
        int t = wu * 8 + tt;
        if (t < cnt) {
            int tk = tokmap[s0 + t];
            float* orow = out + (size_t)tk * OUTD + (size_t)kbase * 64 + lane;
            #pragma unroll
            for (int kk = 0; kk < 4; ++kk)
                __builtin_nontemporal_store(y[tt][kk] + bv[kk], orow + (size_t)kk * 64);
        }
    }
}

extern "C" void kernel_launch(void* const* d_in, const int* in_sizes, int n_in,
                              void* d_out, int out_size, void* d_ws, size_t ws_size,
                              hipStream_t stream) {
    const float* x  = (const float*)d_in[0];
    const float* Wg = (const float*)d_in[1];
    const float* W1 = (const float*)d_in[2];
    const float* W2 = (const float*)d_in[3];
    const float* b  = (const float*)d_in[4];
    float* out = (float*)d_out;

    float*    w1t2 = (float*)d_ws;                            // 2 MB
    uint32_t* xg2p = (uint32_t*)(w1t2 + 524288);              // 16 MB
    uint32_t* zbuf = xg2p + (size_t)512 * NTOK;

    // single-pass if zbuf can hold all 64 k (64 MB); else two passes of 32 MB
    size_t tail_words = (size_t)NTOK + 2 * NTOK + 32 + NPAIR * NTOK;
    size_t need1 = (size_t)524288 * 4 + (size_t)512 * NTOK * 4 +
                   (size_t)2048 * NTOK * 4 + tail_words * 4;
    int onep = (ws_size >= need1) ? 1 : 0;
    size_t zwords = (size_t)(onep ? 2048 : 1024) * NTOK;

    int*   tokmap  = (int*)(zbuf + zwords);                   // 8192 i
    float* wgt     = (float*)(tokmap + NTOK);                 // 16384 f
    int*   pairCnt = (int*)(wgt + 2 * NTOK);                  // 32 i
    int*   bucket  = pairCnt + 32;                            // 28*8192 i

    hipMemsetAsync(pairCnt, 0, 32 * sizeof(int), stream);
    k_w1t2 <<<2048, 256, 0, stream>>>(W1, w1t2);
    k_gate <<<2048, 256, 0, stream>>>(x, Wg, pairCnt, bucket, wgt);
    k_slots<<<32,   256, 0, stream>>>(pairCnt, bucket, tokmap);
    k_xgp  <<<2048, 256, 0, stream>>>(x, tokmap, xg2p);

    int nkbl = onep ? 8 : 4;
    int Q    = nkbl * 4;
    int NH   = onep ? 1 : 2;
    for (int h = 0; h < NH; ++h) {
        k_z<<<MAXTILES * nkbl,     512, 0, stream>>>(w1t2, xg2p, tokmap, wgt, pairCnt, zbuf, h * nkbl, Q);
        k_y<<<MAXTILES * nkbl * 2, 512, 0, stream>>>(W2, b, zbuf, tokmap, pairCnt, out, h * nkbl, Q);
    }
}

// Round 6
// 227.390 us; speedup vs baseline: 3.8500x; 1.3379x over previous
//
#include <hip/hip_runtime.h>
#include <stdint.h>

#define NTOK 8192
#define DIM  1024
#define NE   8
#define NPAIR 28
#define OUTD 4096
#define MAXTILES 155   // >= sum_p ceil(cnt_p/64) worst case (128 + 27)

typedef __attribute__((ext_vector_type(8))) short bf16x8;
typedef __attribute__((ext_vector_type(4))) float f32x4;

static __device__ __forceinline__ unsigned short f2bf(float f) {
    uint32_t u = __float_as_uint(f);
    u += 0x7fffu + ((u >> 16) & 1u);     // RNE
    return (unsigned short)(u >> 16);
}

// ---- K0: weight repacks to bf16 ----
// w1m[e][j][k][i]  (k = kb*8+kk), i contiguous  : 524288 elems
// w2m[e][k][l][j]  j contiguous                 : 1048576 elems
__global__ __launch_bounds__(256) void k_wm(const float* __restrict__ W1,
                                            const float* __restrict__ W2,
                                            unsigned short* __restrict__ w1m,
                                            unsigned short* __restrict__ w2m) {
    int t = blockIdx.x * 256 + threadIdx.x;
    if (t < 524288) {
        int i = t & 31, k = (t >> 5) & 63, j = (t >> 11) & 31, e = (t >> 16) & 7;
        w1m[t] = f2bf(W1[(((j * 32 + i) * 64 + k) * 8) + e]);
    } else {
        int t2 = t - 524288;
        int j = t2 & 31, l = (t2 >> 5) & 63, k = (t2 >> 11) & 63, e = (t2 >> 17) & 7;
        w2m[t2] = f2bf(W2[(((e * 64 + k) * 32 + j) * 64) + l]);
    }
}

// ---- K1: gate (fp32) + pair bucketing ----
__global__ __launch_bounds__(256) void k_gate(const float* __restrict__ x,
                                              const float* __restrict__ Wg,
                                              int* __restrict__ pairCnt,
                                              int* __restrict__ bucket,
                                              float* __restrict__ wgt) {
    __shared__ float sWg[NE][DIM];
    int tid = threadIdx.x;
    #pragma unroll
    for (int u = 0; u < 8; ++u) {
        int idx = u * 1024 + tid * 4;
        *(float4*)&sWg[0][idx] = *(const float4*)&Wg[idx];
    }
    __syncthreads();
    int w = tid >> 6, lane = tid & 63;
    int tok = blockIdx.x * 4 + w;
    float acc[NE];
    #pragma unroll
    for (int e = 0; e < NE; ++e) acc[e] = 0.f;
    const float* xr = x + (size_t)tok * DIM;
    #pragma unroll
    for (int c = 0; c < 4; ++c) {
        float4 xv = *(const float4*)&xr[c * 256 + lane * 4];
        #pragma unroll
        for (int e = 0; e < NE; ++e) {
            float4 wv = *(const float4*)&sWg[e][c * 256 + lane * 4];
            acc[e] += xv.x * wv.x + xv.y * wv.y + xv.z * wv.z + xv.w * wv.w;
        }
    }
    #pragma unroll
    for (int e = 0; e < NE; ++e)
        #pragma unroll
        for (int off = 32; off > 0; off >>= 1)
            acc[e] += __shfl_xor(acc[e], off, 64);
    if (lane == 0) {
        int i1 = 0; float v1 = acc[0];
        for (int e = 1; e < NE; ++e) if (acc[e] > v1) { v1 = acc[e]; i1 = e; }
        int i2 = -1; float v2 = -3.4e38f;
        for (int e = 0; e < NE; ++e) { if (e == i1) continue; if (acc[e] > v2) { v2 = acc[e]; i2 = e; } }
        float ex = expf(v2 - v1);
        float s  = 1.f / (1.f + ex);
        float w1v = s + 1e-6f;
        float w2v = ex * s + 1e-6f;
        int ea = min(i1, i2), eb = max(i1, i2);
        float wa = (i1 < i2) ? w1v : w2v;
        float wb = (i1 < i2) ? w2v : w1v;
        wgt[tok * 2 + 0] = wa;
        wgt[tok * 2 + 1] = wb;
        int pid = ea * 7 - (ea * (ea - 1)) / 2 + (eb - ea - 1);
        int pos = atomicAdd(&pairCnt[pid], 1);
        bucket[pid * NTOK + pos] = tok;
    }
}

// ---- K2: slot -> token map ----
__global__ __launch_bounds__(256) void k_slots(const int* __restrict__ pairCnt,
                                               const int* __restrict__ bucket,
                                               int* __restrict__ tokmap) {
    int s = blockIdx.x * 256 + threadIdx.x;
    int off = 0;
    for (int p = 0; p < NPAIR; ++p) {
        int c = pairCnt[p];
        if (s < off + c) { tokmap[s] = bucket[p * NTOK + (s - off)]; return; }
        off += c;
    }
}

// ---- K3: gather x -> xg3[j][slot][i] bf16 (64-B rows) ----
__global__ __launch_bounds__(256) void k_xg3(const float* __restrict__ x,
                                             const int* __restrict__ tokmap,
                                             unsigned short* __restrict__ xg3) {
    int tid = threadIdx.x;
    int w = tid >> 6, l = tid & 63;
    int j = l & 31, sp = l >> 5;
    int s0 = blockIdx.x * 16;
    #pragma unroll
    for (int pp = 0; pp < 2; ++pp) {
        int slot = s0 + w * 4 + pp * 2 + sp;
        int tok = tokmap[slot];
        const float* xr = x + (size_t)tok * DIM + j;
        float v[32];
        #pragma unroll
        for (int i = 0; i < 32; ++i) v[i] = xr[i * 32];
        unsigned short* orow = xg3 + ((size_t)j * NTOK + slot) * 32;
        #pragma unroll
        for (int ic = 0; ic < 4; ++ic) {
            uint4 pk;
            pk.x = (uint32_t)f2bf(v[ic * 8 + 0]) | ((uint32_t)f2bf(v[ic * 8 + 1]) << 16);
            pk.y = (uint32_t)f2bf(v[ic * 8 + 2]) | ((uint32_t)f2bf(v[ic * 8 + 3]) << 16);
            pk.z = (uint32_t)f2bf(v[ic * 8 + 4]) | ((uint32_t)f2bf(v[ic * 8 + 5]) << 16);
            pk.w = (uint32_t)f2bf(v[ic * 8 + 6]) | ((uint32_t)f2bf(v[ic * 8 + 7]) << 16);
            *(uint4*)(orow + ic * 8) = pk;
        }
    }
}

// helper: tile scan
static __device__ __forceinline__ bool tile_scan(const int* __restrict__ pairCnt,
                                                 int tb, int& p, int& s0, int& cnt) {
    p = -1; s0 = 0; cnt = 0;
    int toff = 0, soff = 0;
    for (int q = 0; q < NPAIR; ++q) {
        int c = pairCnt[q];
        int nt = (c + 63) >> 6;
        if (p < 0 && tb < toff + nt) {
            int lt = tb - toff;
            p = q;
            s0 = soff + lt * 64;
            cnt = min(64, c - lt * 64);
        }
        toff += nt; soff += c;
    }
    return p >= 0;
}

// ---- K4: MFMA z: zbuf[kloc][slot][je] bf16, je = e*32+j, gate-scaled ----
__global__ __launch_bounds__(256) void k_z(const unsigned short* __restrict__ w1m,
                                           const unsigned short* __restrict__ xg3,
                                           const int* __restrict__ tokmap,
                                           const float* __restrict__ wgt,
                                           const int* __restrict__ pairCnt,
                                           unsigned short* __restrict__ zbuf,
                                           int kb0, int nkh) {
    int bid = blockIdx.x;
    int joct = bid & 3;
    int khl  = (bid >> 2) % nkh;
    int tb   = bid / (4 * nkh);

    int p, s0, cnt;
    if (!tile_scan(pairCnt, tb, p, s0, cnt)) return;
    p   = __builtin_amdgcn_readfirstlane(p);
    s0  = __builtin_amdgcn_readfirstlane(s0);
    cnt = __builtin_amdgcn_readfirstlane(cnt);

    int a0 = 0, r0 = p;
    while (r0 >= 7 - a0) { r0 -= 7 - a0; ++a0; }
    int ea = a0, eb = a0 + 1 + r0;

    int tid = threadIdx.x;
    int mt = tid >> 6, l = tid & 63;
    int lr = l & 15, lg = l >> 4;
    int e_lane = lr >> 3, kk = lr & 7;
    int my_e = e_lane ? eb : ea;

    // gate scales per output row r
    float gs[4];
    #pragma unroll
    for (int r = 0; r < 4; ++r) {
        int tok = tokmap[min(s0 + mt * 16 + lg * 4 + r, NTOK - 1)];
        float2 wv = *(const float2*)&wgt[tok * 2];
        gs[r] = e_lane ? wv.y : wv.x;
    }

    // A fragments: x rows for 8 j's (k-label: i = lg*8 + elem)
    bf16x8 a[8];
    int srow = min(s0 + mt * 16 + lr, NTOK - 1);
    #pragma unroll
    for (int jj = 0; jj < 8; ++jj) {
        int j = joct * 8 + jj;
        a[jj] = *(const bf16x8*)(xg3 + ((size_t)j * NTOK + srow) * 32 + lg * 8);
    }

    const f32x4 zero4 = {0.f, 0.f, 0.f, 0.f};
    #pragma unroll
    for (int kb4 = 0; kb4 < 4; ++kb4) {
        int kb = kb0 + khl * 4 + kb4;           // global kb
        f32x4 dj[8];
        #pragma unroll
        for (int jj = 0; jj < 8; ++jj) {
            int j = joct * 8 + jj;
            // B fragment: w1m[e][j][kb*8+kk][i=lg*8..+7]
            bf16x8 b = *(const bf16x8*)(w1m + (((size_t)(my_e * 32 + j) * 64) + kb * 8 + kk) * 32 + lg * 8);
            dj[jj] = __builtin_amdgcn_mfma_f32_16x16x32_bf16(a[jj], b, zero4, 0, 0, 0);
        }
        int kloc = (kb - kb0) * 8 + kk;
        #pragma unroll
        for (int r = 0; r < 4; ++r) {
            int t = mt * 16 + lg * 4 + r;
            if (t < cnt) {
                float g = gs[r];
                uint4 pk;
                pk.x = (uint32_t)f2bf(dj[0][r] * g) | ((uint32_t)f2bf(dj[1][r] * g) << 16);
                pk.y = (uint32_t)f2bf(dj[2][r] * g) | ((uint32_t)f2bf(dj[3][r] * g) << 16);
                pk.z = (uint32_t)f2bf(dj[4][r] * g) | ((uint32_t)f2bf(dj[5][r] * g) << 16);
                pk.w = (uint32_t)f2bf(dj[6][r] * g) | ((uint32_t)f2bf(dj[7][r] * g) << 16);
                *(uint4*)(zbuf + ((size_t)kloc * NTOK + s0 + t) * 64 + e_lane * 32 + joct * 8) = pk;
            }
        }
    }
}

// ---- K5: MFMA y: out[tok][k*64+l] = sum_je z[t][je][k] * w2m[e][k][l][j] + bias ----
__global__ __launch_bounds__(256) void k_y(const unsigned short* __restrict__ w2m,
                                           const float* __restrict__ bias,
                                           const unsigned short* __restrict__ zbuf,
                                           const int* __restrict__ tokmap,
                                           const int* __restrict__ pairCnt,
                                           float* __restrict__ out,
                                           int kb0, int nkbl) {
    __shared__ unsigned short zls[8 * 64 * 64];     // 64 KB, chunk-swizzled
    int bid = blockIdx.x;
    int kbL = bid % nkbl;
    int tb  = bid / nkbl;

    int p, s0, cnt;
    if (!tile_scan(pairCnt, tb, p, s0, cnt)) return;
    p   = __builtin_amdgcn_readfirstlane(p);
    s0  = __builtin_amdgcn_readfirstlane(s0);
    cnt = __builtin_amdgcn_readfirstlane(cnt);

    int a0 = 0, r0 = p;
    while (r0 >= 7 - a0) { r0 -= 7 - a0; ++a0; }
    int ea = a0, eb = a0 + 1 + r0;

    int tid = threadIdx.x;
    int mt = tid >> 6, l = tid & 63;
    int lr = l & 15, lg = l >> 4;
    int kg8 = (kb0 + kbL) * 8;                      // global k base for this block

    // stage z chunk (8 k x 64 t x 64 je) into swizzled LDS
    #pragma unroll
    for (int rr = 0; rr < 2; ++rr) {
        int row = tid + rr * 256;                   // 0..511
        int k = row >> 6, t = row & 63;
        const unsigned short* src = zbuf + ((size_t)(kbL * 8 + k) * NTOK + min(s0 + t, NTOK - 1)) * 64;
        #pragma unroll
        for (int c = 0; c < 8; ++c) {
            uint4 v = *(const uint4*)(src + c * 8);
            *(uint4*)(zls + (size_t)(k * 64 + t) * 64 + ((c ^ (t & 7)) * 8)) = v;
        }
    }
    __syncthreads();

    int tokm[4];
    #pragma unroll
    for (int r = 0; r < 4; ++r)
        tokm[r] = tokmap[min(s0 + mt * 16 + lg * 4 + r, NTOK - 1)];

    const f32x4 zero4 = {0.f, 0.f, 0.f, 0.f};
    #pragma unroll 2
    for (int k = 0; k < 8; ++k) {
        int t = mt * 16 + lr;
        const unsigned short* zb = zls + (size_t)(k * 64 + t) * 64;
        bf16x8 az0 = *(const bf16x8*)(zb + (((0 + lg) ^ (t & 7)) * 8));   // je = lg*8..   (e_local 0 -> ea)
        bf16x8 az1 = *(const bf16x8*)(zb + (((4 + lg) ^ (t & 7)) * 8));   // je = 32+lg*8.. (e_local 1 -> eb)
        int kg = kg8 + k;
        f32x4 acc[4];
        #pragma unroll
        for (int nt = 0; nt < 4; ++nt) acc[nt] = zero4;
        #pragma unroll
        for (int nt = 0; nt < 4; ++nt) {
            bf16x8 b0 = *(const bf16x8*)(w2m + (((size_t)ea * 64 + kg) * 64 + nt * 16 + lr) * 32 + lg * 8);
            acc[nt] = __builtin_amdgcn_mfma_f32_16x16x32_bf16(az0, b0, acc[nt], 0, 0, 0);
            bf16x8 b1 = *(const bf16x8*)(w2m + (((size_t)eb * 64 + kg) * 64 + nt * 16 + lr) * 32 + lg * 8);
            acc[nt] = __builtin_amdgcn_mfma_f32_16x16x32_bf16(az1, b1, acc[nt], 0, 0, 0);
        }
        #pragma unroll
        for (int nt = 0; nt < 4; ++nt) {
            float bv = bias[kg * 64 + nt * 16 + lr];
            #pragma unroll
            for (int r = 0; r < 4; ++r) {
                int t2 = mt * 16 + lg * 4 + r;
                if (t2 < cnt)
                    __builtin_nontemporal_store(acc[nt][r] + bv,
                        out + (size_t)tokm[r] * OUTD + (size_t)kg * 64 + nt * 16 + lr);
            }
        }
    }
}

extern "C" void kernel_launch(void* const* d_in, const int* in_sizes, int n_in,
                              void* d_out, int out_size, void* d_ws, size_t ws_size,
                              hipStream_t stream) {
    const float* x  = (const float*)d_in[0];
    const float* Wg = (const float*)d_in[1];
    const float* W1 = (const float*)d_in[2];
    const float* W2 = (const float*)d_in[3];
    const float* b  = (const float*)d_in[4];
    float* out = (float*)d_out;

    unsigned short* w1m = (unsigned short*)d_ws;            // 1 MB
    unsigned short* w2m = w1m + 524288;                     // 2 MB
    unsigned short* xg3 = w2m + 1048576;                    // 16 MB
    unsigned short* zbuf = xg3 + 8388608;                   // 64 MB (or 32 MB two-pass)

    // single-pass needs 87,130,240 B of ws; else two k-halves of 32 MB
    size_t need1 = ((size_t)524288 + 1048576 + 8388608 + 33554432) * 2 +
                   ((size_t)NTOK + 2 * NTOK + 32) * 4;
    int onep = (ws_size >= need1) ? 1 : 0;
    size_t zwords = (size_t)(onep ? 33554432 : 16777216);

    int*   tokmap  = (int*)(zbuf + zwords);
    float* wgt     = (float*)(tokmap + NTOK);
    int*   pairCnt = (int*)(wgt + 2 * NTOK);
    int*   bucket  = (int*)xg3;                             // aliased: dead before k_xg3 runs

    hipMemsetAsync(pairCnt, 0, 32 * sizeof(int), stream);
    k_gate <<<2048, 256, 0, stream>>>(x, Wg, pairCnt, bucket, wgt);
    k_slots<<<32,   256, 0, stream>>>(pairCnt, bucket, tokmap);
    k_wm   <<<6144, 256, 0, stream>>>(W1, W2, w1m, w2m);
    k_xg3  <<<512,  256, 0, stream>>>(x, tokmap, xg3);

    if (onep) {
        k_z<<<MAXTILES * 8, 256, 0, stream>>>(w1m, xg3, tokmap, wgt, pairCnt, zbuf, 0, 2);
        k_y<<<MAXTILES * 8, 256, 0, stream>>>(w2m, b, zbuf, tokmap, pairCnt, out, 0, 8);
    } else {
        for (int h = 0; h < 2; ++h) {
            k_z<<<MAXTILES * 4, 256, 0, stream>>>(w1m, xg3, tokmap, wgt, pairCnt, zbuf, h * 4, 1);
            k_y<<<MAXTILES * 4, 256, 0, stream>>>(w2m, b, zbuf, tokmap, pairCnt, out, h * 4, 4);
        }
    }
}

// Round 7
// 218.155 us; speedup vs baseline: 4.0130x; 1.0423x over previous
//
#include <hip/hip_runtime.h>
#include <stdint.h>

#define NTOK 8192
#define DIM  1024
#define NE   8
#define NPAIR 28
#define OUTD 4096
#define MAXTILES 155   // >= sum_p ceil(cnt_p/64) worst case (128 + 27)

typedef __attribute__((ext_vector_type(8))) short bf16x8;
typedef __attribute__((ext_vector_type(4))) float f32x4;

static __device__ __forceinline__ unsigned short f2bf(float f) {
    uint32_t u = __float_as_uint(f);
    u += 0x7fffu + ((u >> 16) & 1u);     // RNE
    return (unsigned short)(u >> 16);
}

// ---- K0: weight repacks to bf16 ----
// w1m[e][j][k][i]  (k = kb*8+kk), i contiguous  : 524288 elems
// w2m[e][k][l][j]  j contiguous                 : 1048576 elems
__global__ __launch_bounds__(256) void k_wm(const float* __restrict__ W1,
                                            const float* __restrict__ W2,
                                            unsigned short* __restrict__ w1m,
                                            unsigned short* __restrict__ w2m) {
    int t = blockIdx.x * 256 + threadIdx.x;
    if (t < 524288) {
        int i = t & 31, k = (t >> 5) & 63, j = (t >> 11) & 31, e = (t >> 16) & 7;
        w1m[t] = f2bf(W1[(((j * 32 + i) * 64 + k) * 8) + e]);
    } else {
        int t2 = t - 524288;
        int j = t2 & 31, l = (t2 >> 5) & 63, k = (t2 >> 11) & 63, e = (t2 >> 17) & 7;
        w2m[t2] = f2bf(W2[(((e * 64 + k) * 32 + j) * 64) + l]);
    }
}

// ---- K1: gate (fp32) + pair bucketing ----
__global__ __launch_bounds__(256) void k_gate(const float* __restrict__ x,
                                              const float* __restrict__ Wg,
                                              int* __restrict__ pairCnt,
                                              int* __restrict__ bucket,
                                              float* __restrict__ wgt) {
    __shared__ float sWg[NE][DIM];
    int tid = threadIdx.x;
    #pragma unroll
    for (int u = 0; u < 8; ++u) {
        int idx = u * 1024 + tid * 4;
        *(float4*)&sWg[0][idx] = *(const float4*)&Wg[idx];
    }
    __syncthreads();
    int w = tid >> 6, lane = tid & 63;
    int tok = blockIdx.x * 4 + w;
    float acc[NE];
    #pragma unroll
    for (int e = 0; e < NE; ++e) acc[e] = 0.f;
    const float* xr = x + (size_t)tok * DIM;
    #pragma unroll
    for (int c = 0; c < 4; ++c) {
        float4 xv = *(const float4*)&xr[c * 256 + lane * 4];
        #pragma unroll
        for (int e = 0; e < NE; ++e) {
            float4 wv = *(const float4*)&sWg[e][c * 256 + lane * 4];
            acc[e] += xv.x * wv.x + xv.y * wv.y + xv.z * wv.z + xv.w * wv.w;
        }
    }
    #pragma unroll
    for (int e = 0; e < NE; ++e)
        #pragma unroll
        for (int off = 32; off > 0; off >>= 1)
            acc[e] += __shfl_xor(acc[e], off, 64);
    if (lane == 0) {
        int i1 = 0; float v1 = acc[0];
        for (int e = 1; e < NE; ++e) if (acc[e] > v1) { v1 = acc[e]; i1 = e; }
        int i2 = -1; float v2 = -3.4e38f;
        for (int e = 0; e < NE; ++e) { if (e == i1) continue; if (acc[e] > v2) { v2 = acc[e]; i2 = e; } }
        float ex = expf(v2 - v1);
        float s  = 1.f / (1.f + ex);
        float w1v = s + 1e-6f;
        float w2v = ex * s + 1e-6f;
        int ea = min(i1, i2), eb = max(i1, i2);
        float wa = (i1 < i2) ? w1v : w2v;
        float wb = (i1 < i2) ? w2v : w1v;
        wgt[tok * 2 + 0] = wa;
        wgt[tok * 2 + 1] = wb;
        int pid = ea * 7 - (ea * (ea - 1)) / 2 + (eb - ea - 1);
        int pos = atomicAdd(&pairCnt[pid], 1);
        bucket[pid * NTOK + pos] = tok;
    }
}

// ---- K2: slot -> token map + tile descriptors ----
__global__ __launch_bounds__(256) void k_slots(const int* __restrict__ pairCnt,
                                               const int* __restrict__ bucket,
                                               int* __restrict__ tokmap,
                                               int4* __restrict__ tileDesc) {
    int s = blockIdx.x * 256 + threadIdx.x;
    // tokmap
    {
        int off = 0;
        for (int p = 0; p < NPAIR; ++p) {
            int c = pairCnt[p];
            if (s < off + c) { tokmap[s] = bucket[p * NTOK + (s - off)]; break; }
            off += c;
        }
    }
    // tile descriptors
    if (s < MAXTILES) {
        int4 d; d.x = -1; d.y = 0; d.z = 0; d.w = 0;
        int toff = 0, soff = 0;
        for (int q = 0; q < NPAIR; ++q) {
            int c = pairCnt[q];
            int nt = (c + 63) >> 6;
            if (d.x < 0 && s < toff + nt) {
                int lt = s - toff;
                d.x = q;
                d.y = soff + lt * 64;
                d.z = min(64, c - lt * 64);
            }
            toff += nt; soff += c;
        }
        tileDesc[s] = d;
    }
}

// ---- K3: gather x -> xg3[j][slot][i] bf16 (64-B rows), LDS transpose ----
__global__ __launch_bounds__(256) void k_xg3(const float* __restrict__ x,
                                             const int* __restrict__ tokmap,
                                             unsigned short* __restrict__ xg3) {
    __shared__ float tile[8][1056];                 // pad +1 per 32: bank = (i+j)&31
    int s0 = blockIdx.x * 8;
    int tid = threadIdx.x;
    int r = tid >> 5, c = tid & 31;
    int tok = tokmap[s0 + r];
    const float* xr = x + (size_t)tok * DIM;
    #pragma unroll
    for (int u = 0; u < 8; ++u) {
        int d = u * 128 + c * 4;
        float4 v = *(const float4*)&xr[d];
        int d2 = d + (d >> 5);
        tile[r][d2 + 0] = v.x; tile[r][d2 + 1] = v.y;
        tile[r][d2 + 2] = v.z; tile[r][d2 + 3] = v.w;
    }
    __syncthreads();
    int sl = tid >> 5, j = tid & 31;                // thread -> (slot, j)
    float v[32];
    #pragma unroll
    for (int i = 0; i < 32; ++i) v[i] = tile[sl][i * 33 + j];
    unsigned short* orow = xg3 + ((size_t)j * NTOK + s0 + sl) * 32;
    #pragma unroll
    for (int ic = 0; ic < 4; ++ic) {
        uint4 pk;
        pk.x = (uint32_t)f2bf(v[ic * 8 + 0]) | ((uint32_t)f2bf(v[ic * 8 + 1]) << 16);
        pk.y = (uint32_t)f2bf(v[ic * 8 + 2]) | ((uint32_t)f2bf(v[ic * 8 + 3]) << 16);
        pk.z = (uint32_t)f2bf(v[ic * 8 + 4]) | ((uint32_t)f2bf(v[ic * 8 + 5]) << 16);
        pk.w = (uint32_t)f2bf(v[ic * 8 + 6]) | ((uint32_t)f2bf(v[ic * 8 + 7]) << 16);
        *(uint4*)(orow + ic * 8) = pk;
    }
}

// ---- K4: MFMA z: zbuf[kloc][slot][je] bf16, je = e*32+j, gate-scaled ----
__global__ __launch_bounds__(256) void k_z(const unsigned short* __restrict__ w1m,
                                           const unsigned short* __restrict__ xg3,
                                           const int* __restrict__ tokmap,
                                           const float* __restrict__ wgt,
                                           const int4* __restrict__ tileDesc,
                                           unsigned short* __restrict__ zbuf,
                                           int kb0, int nkh) {
    int bid = blockIdx.x;
    int joct = bid & 3;
    int khl  = (bid >> 2) % nkh;
    int tb   = bid / (4 * nkh);

    int4 td = tileDesc[tb];
    int p = td.x, s0 = td.y, cnt = td.z;
    if (p < 0) return;

    int a0 = 0, r0 = p;
    while (r0 >= 7 - a0) { r0 -= 7 - a0; ++a0; }
    int ea = a0, eb = a0 + 1 + r0;

    int tid = threadIdx.x;
    int mt = tid >> 6, l = tid & 63;
    int lr = l & 15, lg = l >> 4;
    int e_lane = lr >> 3, kk = lr & 7;
    int my_e = e_lane ? eb : ea;

    // gate scales per output row r
    float gs[4];
    #pragma unroll
    for (int r = 0; r < 4; ++r) {
        int tok = tokmap[min(s0 + mt * 16 + lg * 4 + r, NTOK - 1)];
        float2 wv = *(const float2*)&wgt[tok * 2];
        gs[r] = e_lane ? wv.y : wv.x;
    }

    // A fragments: x rows for 8 j's (k-label: i = lg*8 + elem)
    bf16x8 a[8];
    int srow = min(s0 + mt * 16 + lr, NTOK - 1);
    #pragma unroll
    for (int jj = 0; jj < 8; ++jj) {
        int j = joct * 8 + jj;
        a[jj] = *(const bf16x8*)(xg3 + ((size_t)j * NTOK + srow) * 32 + lg * 8);
    }

    const f32x4 zero4 = {0.f, 0.f, 0.f, 0.f};
    #pragma unroll
    for (int kb4 = 0; kb4 < 4; ++kb4) {
        int kb = kb0 + khl * 4 + kb4;           // global kb
        f32x4 dj[8];
        #pragma unroll
        for (int jj = 0; jj < 8; ++jj) {
            int j = joct * 8 + jj;
            bf16x8 b = *(const bf16x8*)(w1m + (((size_t)(my_e * 32 + j) * 64) + kb * 8 + kk) * 32 + lg * 8);
            dj[jj] = __builtin_amdgcn_mfma_f32_16x16x32_bf16(a[jj], b, zero4, 0, 0, 0);
        }
        int kloc = (khl * 4 + kb4) * 8 + kk;
        #pragma unroll
        for (int r = 0; r < 4; ++r) {
            int t = mt * 16 + lg * 4 + r;
            if (t < cnt) {
                float g = gs[r];
                uint4 pk;
                pk.x = (uint32_t)f2bf(dj[0][r] * g) | ((uint32_t)f2bf(dj[1][r] * g) << 16);
                pk.y = (uint32_t)f2bf(dj[2][r] * g) | ((uint32_t)f2bf(dj[3][r] * g) << 16);
                pk.z = (uint32_t)f2bf(dj[4][r] * g) | ((uint32_t)f2bf(dj[5][r] * g) << 16);
                pk.w = (uint32_t)f2bf(dj[6][r] * g) | ((uint32_t)f2bf(dj[7][r] * g) << 16);
                *(uint4*)(zbuf + ((size_t)kloc * NTOK + s0 + t) * 64 + e_lane * 32 + joct * 8) = pk;
            }
        }
    }
}

// ---- K5: MFMA y — direct A-frag loads (sector-perfect), no LDS, no barrier ----
__global__ __launch_bounds__(256, 4) void k_y(const unsigned short* __restrict__ w2m,
                                              const float* __restrict__ bias,
                                              const unsigned short* __restrict__ zbuf,
                                              const int* __restrict__ tokmap,
                                              const int4* __restrict__ tileDesc,
                                              float* __restrict__ out,
                                              int kb0, int nkbl) {
    int bid = blockIdx.x;
    int kbL = bid % nkbl;
    int tb  = bid / nkbl;

    int4 td = tileDesc[tb];
    int p = td.x, s0 = td.y, cnt = td.z;
    if (p < 0) return;

    int a0 = 0, r0 = p;
    while (r0 >= 7 - a0) { r0 -= 7 - a0; ++a0; }
    int ea = a0, eb = a0 + 1 + r0;

    int tid = threadIdx.x;
    int mt = tid >> 6, l = tid & 63;
    int lr = l & 15, lg = l >> 4;
    int kg8 = (kb0 + kbL) * 8;

    // prefetch all A-fragments: z[t=mt*16+lr][je][k] for 8 k, both je halves
    int tA = min(s0 + mt * 16 + lr, NTOK - 1);
    const unsigned short* zb = zbuf + ((size_t)(kbL * 8) * NTOK + tA) * 64;
    bf16x8 az[8][2];
    #pragma unroll
    for (int k = 0; k < 8; ++k) {
        az[k][0] = *(const bf16x8*)(zb + (size_t)k * NTOK * 64 + lg * 8);        // je = lg*8..      (-> ea)
        az[k][1] = *(const bf16x8*)(zb + (size_t)k * NTOK * 64 + 32 + lg * 8);   // je = 32 + lg*8.. (-> eb)
    }

    int tokm[4];
    #pragma unroll
    for (int r = 0; r < 4; ++r)
        tokm[r] = tokmap[min(s0 + mt * 16 + lg * 4 + r, NTOK - 1)];

    const f32x4 zero4 = {0.f, 0.f, 0.f, 0.f};
    #pragma unroll 2
    for (int k = 0; k < 8; ++k) {
        int kg = kg8 + k;
        f32x4 acc[4];
        #pragma unroll
        for (int nt = 0; nt < 4; ++nt) acc[nt] = zero4;
        #pragma unroll
        for (int nt = 0; nt < 4; ++nt) {
            bf16x8 b0 = *(const bf16x8*)(w2m + (((size_t)ea * 64 + kg) * 64 + nt * 16 + lr) * 32 + lg * 8);
            acc[nt] = __builtin_amdgcn_mfma_f32_16x16x32_bf16(az[k][0], b0, acc[nt], 0, 0, 0);
            bf16x8 b1 = *(const bf16x8*)(w2m + (((size_t)eb * 64 + kg) * 64 + nt * 16 + lr) * 32 + lg * 8);
            acc[nt] = __builtin_amdgcn_mfma_f32_16x16x32_bf16(az[k][1], b1, acc[nt], 0, 0, 0);
        }
        #pragma unroll
        for (int nt = 0; nt < 4; ++nt) {
            float bv = bias[kg * 64 + nt * 16 + lr];
            #pragma unroll
            for (int r = 0; r < 4; ++r) {
                int t2 = mt * 16 + lg * 4 + r;
                if (t2 < cnt)
                    __builtin_nontemporal_store(acc[nt][r] + bv,
                        out + (size_t)tokm[r] * OUTD + (size_t)kg * 64 + nt * 16 + lr);
            }
        }
    }
}

extern "C" void kernel_launch(void* const* d_in, const int* in_sizes, int n_in,
                              void* d_out, int out_size, void* d_ws, size_t ws_size,
                              hipStream_t stream) {
    const float* x  = (const float*)d_in[0];
    const float* Wg = (const float*)d_in[1];
    const float* W1 = (const float*)d_in[2];
    const float* W2 = (const float*)d_in[3];
    const float* b  = (const float*)d_in[4];
    float* out = (float*)d_out;

    unsigned short* w1m = (unsigned short*)d_ws;            // 1 MB
    unsigned short* w2m = w1m + 524288;                     // 2 MB
    unsigned short* xg3 = w2m + 1048576;                    // 16 MB
    unsigned short* zbuf = xg3 + 8388608;                   // 64 MB (or 32 MB two-pass)

    size_t need1 = ((size_t)524288 + 1048576 + 8388608 + 33554432) * 2 +
                   ((size_t)NTOK + 2 * NTOK + 32) * 4 + (size_t)MAXTILES * 16;
    int onep = (ws_size >= need1) ? 1 : 0;
    size_t zwords = (size_t)(onep ? 33554432 : 16777216);

    int*   tokmap   = (int*)(zbuf + zwords);
    float* wgt      = (float*)(tokmap + NTOK);
    int*   pairCnt  = (int*)(wgt + 2 * NTOK);
    int4*  tileDesc = (int4*)(pairCnt + 32);
    int*   bucket   = (int*)xg3;                            // aliased: dead before k_xg3 runs

    hipMemsetAsync(pairCnt, 0, 32 * sizeof(int), stream);
    k_gate <<<2048, 256, 0, stream>>>(x, Wg, pairCnt, bucket, wgt);
    k_slots<<<32,   256, 0, stream>>>(pairCnt, bucket, tokmap, tileDesc);
    k_wm   <<<6144, 256, 0, stream>>>(W1, W2, w1m, w2m);
    k_xg3  <<<1024, 256, 0, stream>>>(x, tokmap, xg3);

    if (onep) {
        k_z<<<MAXTILES * 8, 256, 0, stream>>>(w1m, xg3, tokmap, wgt, tileDesc, zbuf, 0, 2);
        k_y<<<MAXTILES * 8, 256, 0, stream>>>(w2m, b, zbuf, tokmap, tileDesc, out, 0, 8);
    } else {
        for (int h = 0; h < 2; ++h) {
            k_z<<<MAXTILES * 4, 256, 0, stream>>>(w1m, xg3, tokmap, wgt, tileDesc, zbuf, h * 4, 1);
            k_y<<<MAXTILES * 4, 256, 0, stream>>>(w2m, b, zbuf, tokmap, tileDesc, out, h * 4, 4);
        }
    }
}